// Round 8
// baseline (317.694 us; speedup 1.0000x reference)
//
#include <hip/hip_runtime.h>

#define NPT 16384
#define NEG_INF (-3.402823466e38f)

// ---- workspace byte offsets ----
#define OFF_PTS4  0u            // 16384 * 16          = 262144
#define OFF_WKC   262144u       // 128*128*4           = 65536
#define OFF_WAX   327680u       // 64*4*4              = 1024
#define OFF_WBX   328704u       // 1024
#define OFF_CBX   329728u       // 256
#define OFF_CBF   329984u       // 256
#define OFF_WUP   330240u       // 128*16*4            = 8192
#define OFF_BUP   338432u       // 512
#define OFF_TAU   338944u       // 16384*4             = 65536
#define OFF_CNT   404480u       // u8[16384][16]       = 262144
#define OFF_KNN   666624u       // 16384*20*4          = 1310720
#define OFF_PART  1977344u      // 256*16*4            = 16384
#define OFF_CH    1993728u      // 256
#define OFF_R     1994240u      // reused: push u16[16384][16][64] = 33554432 (ends 35.55MB)
                                // after ksel: G(8MB), T2(8MB), F(8MB), F1(1MB), F2(1MB), SP(64KB)

__device__ __forceinline__ float pd_score(float qx2, float qy2, float qz2, float4 c) {
    // fast screening score = 2*dot(q,c) - |c|^2 (query-constant -|q|^2 dropped; same ranking)
    return fmaf(qx2, c.x, fmaf(qy2, c.y, fmaf(qz2, c.z, -c.w)));
}

__device__ __forceinline__ unsigned sortable_f(float v) {
    unsigned b = __float_as_uint(v);
    return (b & 0x80000000u) ? ~b : (b | 0x80000000u);
}

// ---------------- kernel 1: weight folds + pts4 ----------------
__global__ __launch_bounds__(256) void kprep(
    const float* __restrict__ xyz,
    const float* __restrict__ w1, const float* __restrict__ b1,
    const float* __restrict__ g1, const float* __restrict__ bb1,
    const float* __restrict__ m1, const float* __restrict__ v1,
    const float* __restrict__ w2, const float* __restrict__ b2,
    const float* __restrict__ g2, const float* __restrict__ bb2,
    const float* __restrict__ m2, const float* __restrict__ v2,
    const float* __restrict__ wup, const float* __restrict__ bup,
    const float* __restrict__ gu, const float* __restrict__ bu2,
    const float* __restrict__ mu, const float* __restrict__ vu,
    float* __restrict__ wsf)
{
    const int tid = threadIdx.x;
    if (blockIdx.x == 0) {
        float* WKC = wsf + OFF_WKC/4;
        float* WAX = wsf + OFF_WAX/4;
        float* WBX = wsf + OFF_WBX/4;
        float* CBX = wsf + OFF_CBX/4;
        float* CBF = wsf + OFF_CBF/4;
        float* WUP = wsf + OFF_WUP/4;
        float* BUP = wsf + OFF_BUP/4;
        for (int i = tid; i < 16384; i += 256) {
            int c = i >> 7, o = i & 127, oo = o & 63;
            float s2 = g2[oo] * rsqrtf(v2[oo] + 1e-5f);
            float val = (o < 64) ? s2 * w2[oo*256 + c]
                                 : s2 * (w2[oo*256 + 128 + c] - w2[oo*256 + c]);
            WKC[c*128 + o] = val;
        }
        if (tid < 64) {
            int o = tid;
            float s1 = g1[o] * rsqrtf(v1[o] + 1e-5f);
            WAX[o*4+0] = s1 * w1[o*6+0];
            WAX[o*4+1] = s1 * w1[o*6+1];
            WAX[o*4+2] = s1 * w1[o*6+2];
            WAX[o*4+3] = 0.f;
            WBX[o*4+0] = s1 * (w1[o*6+3] - w1[o*6+0]);
            WBX[o*4+1] = s1 * (w1[o*6+4] - w1[o*6+1]);
            WBX[o*4+2] = s1 * (w1[o*6+5] - w1[o*6+2]);
            WBX[o*4+3] = 0.f;
            CBX[o] = s1 * b1[o] + (bb1[o] - m1[o]*s1);
            float s2b = g2[o] * rsqrtf(v2[o] + 1e-5f);
            CBF[o] = s2b * b2[o] + (bb2[o] - m2[o]*s2b);
        }
        if (tid < 128) {
            int o = tid;
            float su = gu[o] * rsqrtf(vu[o] + 1e-5f);
            for (int c = 0; c < 16; ++c) WUP[o*16+c] = su * wup[o*16+c];
            BUP[o] = su * bup[o] + (bu2[o] - mu[o]*su);
        }
    } else {
        // np-f32-exact |p|^2: ((x*x + y*y) + z*z), no FMA contraction, matching
        // np.sum(xyz*xyz, axis=1) sequential f32 reduction.
        #pragma clang fp contract(off)
        int n = (blockIdx.x - 1)*256 + tid;
        float x = xyz[n], y = xyz[NPT+n], z = xyz[2*NPT+n];
        float4 p; p.x = x; p.y = y; p.z = z;
        p.w = (x*x + y*y) + z*z;
        ((float4*)(wsf + OFF_PTS4/4))[n] = p;
    }
}

// ---------------- kernel 2: per-query threshold tau ----------------
// tau[q] = (20th-largest of union(8 per-thread top-6) over candidates [0,1024)) - margin.
// union-20th <= subset-20th <= full-20th, and the 5e-4 margin covers all screening-score
// vs np-f32-pd discrepancies (<= ~3e-5) -> push survivors are a superset of np's top-20.
__global__ __launch_bounds__(256) void ktau(const float* __restrict__ wsf, float* __restrict__ tau)
{
    const float4* pts4 = (const float4*)(wsf + OFF_PTS4/4);
    __shared__ float4 sp[1024];
    __shared__ float t6[32][8][6];
    const int tid = threadIdx.x;
    for (int i = tid; i < 1024; i += 256) sp[i] = pts4[i];
    __syncthreads();
    const int ql = tid >> 3, t = tid & 7;
    const int q = blockIdx.x*32 + ql;
    float4 qp = pts4[q];
    float qx2 = qp.x + qp.x, qy2 = qp.y + qp.y, qz2 = qp.z + qp.z;
    float v0 = NEG_INF, v1 = NEG_INF, v2 = NEG_INF, v3 = NEG_INF, v4 = NEG_INF, v5 = NEG_INF;
    const int jb = t*128;
    for (int i = 0; i < 128; ++i) {
        float v = pd_score(qx2, qy2, qz2, sp[jb + i]);
        float n5 = v > v5 ? (v > v4 ? v4 : v) : v5;
        float n4 = v > v4 ? (v > v3 ? v3 : v) : v4;
        float n3 = v > v3 ? (v > v2 ? v2 : v) : v3;
        float n2 = v > v2 ? (v > v1 ? v1 : v) : v2;
        float n1 = v > v1 ? (v > v0 ? v0 : v) : v1;
        float n0 = v > v0 ? v : v0;
        v0 = n0; v1 = n1; v2 = n2; v3 = n3; v4 = n4; v5 = n5;
    }
    t6[ql][t][0] = v0; t6[ql][t][1] = v1; t6[ql][t][2] = v2;
    t6[ql][t][3] = v3; t6[ql][t][4] = v4; t6[ql][t][5] = v5;
    __syncthreads();
    if (t == 0) {
        int p0=0,p1=0,p2=0,p3=0,p4=0,p5=0,p6=0,p7=0;
        float last = NEG_INF;
        for (int it = 0; it < 20; ++it) {
            float best = NEG_INF; int bl = -1;
#define CHK(L, PL) { float h = t6[ql][L][(PL) < 6 ? (PL) : 5]; if (((PL) < 6) && (h > best)) { best = h; bl = L; } }
            CHK(0,p0) CHK(1,p1) CHK(2,p2) CHK(3,p3) CHK(4,p4) CHK(5,p5) CHK(6,p6) CHK(7,p7)
#undef CHK
            p0 += (bl==0); p1 += (bl==1); p2 += (bl==2); p3 += (bl==3);
            p4 += (bl==4); p5 += (bl==5); p6 += (bl==6); p7 += (bl==7);
            last = best;
        }
        tau[q] = last - 5e-4f;   // conservative margin (covers fmaf-chain vs np-f32 rounding)
    }
}

// ---------------- kernel 3: streaming push-scan, scalar-candidate form ----------------
// Candidate index (jbase+jj) is wave-uniform -> compiler emits s_load through the scalar
// cache for pts4[...]: NO LDS traffic (round-7 profile: broadcast ds_read_b128 was the
// 84us wall = 4.2M reads x 12cyc / 256CU). Per candidate: v_mul + 2 v_fma + v_add +
// v_cmp, each with <=1 SGPR operand. Compare re-associated to 2q.c >= tau + |c|^2;
// the 5e-4 tau margin covers the <=~1e-5 rounding delta vs ktau's fma-chain score.
__global__ __launch_bounds__(256) void kpush(const float* __restrict__ wsf,
                                             const float* __restrict__ tau,
                                             unsigned short* __restrict__ push,
                                             unsigned char* __restrict__ cnt)
{
    const float4* pts4 = (const float4*)(wsf + OFF_PTS4/4);
    const int qg = blockIdx.x >> 4, c = blockIdx.x & 15;
    const int tid = threadIdx.x;
    const int jbase = c * 1024;
    const int q = qg*256 + tid;
    float4 a = pts4[q];
    float ax2 = a.x + a.x, ay2 = a.y + a.y, az2 = a.z + a.z;
    float t0 = tau[q];
    unsigned short* p0 = push + ((size_t)q*16 + c)*64;
    int cw = 0;
    for (int jj = 0; jj < 1024; jj += 4) {
        float4 d0 = pts4[jbase + jj];
        float4 d1 = pts4[jbase + jj + 1];
        float4 d2 = pts4[jbase + jj + 2];
        float4 d3 = pts4[jbase + jj + 3];
        float s0 = fmaf(az2, d0.z, fmaf(ay2, d0.y, ax2*d0.x));
        float s1 = fmaf(az2, d1.z, fmaf(ay2, d1.y, ax2*d1.x));
        float s2 = fmaf(az2, d2.z, fmaf(ay2, d2.y, ax2*d2.x));
        float s3 = fmaf(az2, d3.z, fmaf(ay2, d3.y, ax2*d3.x));
        if (s0 >= t0 + d0.w && cw < 64) { p0[cw] = (unsigned short)(jbase + jj);     ++cw; }
        if (s1 >= t0 + d1.w && cw < 64) { p0[cw] = (unsigned short)(jbase + jj + 1); ++cw; }
        if (s2 >= t0 + d2.w && cw < 64) { p0[cw] = (unsigned short)(jbase + jj + 2); ++cw; }
        if (s3 >= t0 + d3.w && cw < 64) { p0[cw] = (unsigned short)(jbase + jj + 3); ++cw; }
    }
    cnt[q*16 + c] = (unsigned char)cw;
}

// ---------------- kernel 4: exact top-20, wave-per-query register extraction ----------
// One 64-lane wave per query. Lane L owns chunk L>>2, entries (L&3)+4k of that push
// list (~5 survivors/lane), scored np-f32 bit-exact:
//   d = ((x*x' + y*y') + z*z');  pd = ((2f*d - xx_q) - xx_c)   [fp contract off]
// and inserted into a 12-deep NAMED-register descending list (no scratch, no LDS).
// Then 20 rounds of {wave-wide u64 max via shfl_xor; owning lane pops}. Keys embed the
// inverted index -> unique -> exact np top_k order incl. lowest-index tie-breaks.
// Coverage: survivors are a superset of np-top-20 (tau margin); a lane would need >12
// of the global top-20 in its (chunk,residue) bucket to drop one (P ~ 1e-13, fixed data).
#define KS(A,B) V##A = (kk > V##B) ? V##B : ((kk > V##A) ? kk : V##A);
__global__ __launch_bounds__(256) void ksel(const float* __restrict__ wsf,
                                            const unsigned short* __restrict__ push,
                                            const unsigned char* __restrict__ cnt,
                                            unsigned* __restrict__ knn)
{
    #pragma clang fp contract(off)
    const float4* pts4 = (const float4*)(wsf + OFF_PTS4/4);
    const int lane = threadIdx.x & 63;
    const int q = blockIdx.x*4 + (threadIdx.x >> 6);
    float4 qp = pts4[q];

    unsigned long long V0=0,V1=0,V2=0,V3=0,V4=0,V5=0,V6=0,V7=0,V8=0,V9=0,V10=0,V11=0;

    const int c = lane >> 2, sub = lane & 3;
    int nc = (int)cnt[q*16 + c]; if (nc > 64) nc = 64;
    const unsigned short* lp = push + ((size_t)q*16 + c)*64;
    for (int i = sub; i < nc; i += 4) {
        int j = (int)lp[i];
        float4 cp = pts4[j];
        float d  = (qp.x*cp.x + qp.y*cp.y) + qp.z*cp.z;
        float pd = (2.0f*d - qp.w) - cp.w;
        unsigned long long kk = ((unsigned long long)sortable_f(pd) << 14)
                              | (unsigned long long)(16383 - j);
        if (kk > V11) {
            KS(11,10) KS(10,9) KS(9,8) KS(8,7) KS(7,6) KS(6,5)
            KS(5,4) KS(4,3) KS(3,2) KS(2,1) KS(1,0)
            V0 = (kk > V0) ? kk : V0;
        }
    }

    unsigned* kout = knn + (size_t)q*20;
    for (int it = 0; it < 20; ++it) {
        unsigned long long m = V0;
#pragma unroll
        for (int off = 32; off; off >>= 1) {
            unsigned long long o = __shfl_xor(m, off, 64);
            m = (o > m) ? o : m;
        }
        if (lane == 0) kout[it] = 16383u - (unsigned)(m & 0x3FFFull);
        bool own = (V0 == m);
        V0  = own ? V1  : V0;
        V1  = own ? V2  : V1;
        V2  = own ? V3  : V2;
        V3  = own ? V4  : V3;
        V4  = own ? V5  : V4;
        V5  = own ? V6  : V5;
        V6  = own ? V7  : V6;
        V7  = own ? V8  : V7;
        V8  = own ? V9  : V8;
        V9  = own ? V10 : V9;
        V10 = own ? V11 : V10;
        V11 = own ? 0ull : V11;
    }
}

// ---------------- kernel 5: GEMM for feature part of G and T2 ----------------
// G[n][64+o] = F_n . WA_f[o]   ;  T2[n][64+o] = F_n . WB_f[o] + CB_f[o]
__global__ __launch_bounds__(128) void kgemm(const float* __restrict__ feat,
                                             const float* __restrict__ wsf,
                                             float* __restrict__ G, float* __restrict__ T2)
{
    __shared__ float As[32][64];
    __shared__ float Bs[32][128];
    const float* WKC = wsf + OFF_WKC/4;
    const float* CBF = wsf + OFF_CBF/4;
    const int tid = threadIdx.x;
    const int n0 = blockIdx.x * 64;
    const int tx = tid & 15, ty = tid >> 4;
    float acc[8][8] = {};
    for (int kc = 0; kc < 4; ++kc) {
        int c0 = kc * 32;
        for (int i = tid; i < 2048; i += 128) {
            int cl = i >> 6, nl = i & 63;
            As[cl][nl] = feat[(size_t)(c0 + cl)*NPT + n0 + nl];
        }
        for (int i = tid; i < 4096; i += 128) {
            int cl = i >> 7, ol = i & 127;
            Bs[cl][ol] = WKC[(c0 + cl)*128 + ol];
        }
        __syncthreads();
        for (int cc = 0; cc < 32; ++cc) {
            float av[8], bv[8];
#pragma unroll
            for (int r = 0; r < 8; ++r) av[r] = As[cc][ty*8 + r];
#pragma unroll
            for (int s = 0; s < 8; ++s) bv[s] = Bs[cc][tx*8 + s];
#pragma unroll
            for (int r = 0; r < 8; ++r)
#pragma unroll
                for (int s = 0; s < 8; ++s)
                    acc[r][s] = fmaf(av[r], bv[s], acc[r][s]);
        }
        __syncthreads();
    }
#pragma unroll
    for (int r = 0; r < 8; ++r) {
        int n = n0 + ty*8 + r;
        if (tx < 8) {
            float* dst = G + (size_t)n*128 + 64 + tx*8;
#pragma unroll
            for (int s = 0; s < 8; ++s) dst[s] = acc[r][s];
        } else {
            int ob = (tx - 8)*8;
            float* dst = T2 + (size_t)n*128 + 64 + ob;
#pragma unroll
            for (int s = 0; s < 8; ++s) dst[s] = acc[r][s] + CBF[ob + s];
        }
    }
}

// ---------------- kernel 6: xyz part of G and T2 ----------------
__global__ __launch_bounds__(256) void kxpart(const float* __restrict__ xyz,
                                              const float* __restrict__ wsf,
                                              float* __restrict__ G, float* __restrict__ T2)
{
    const float4* WAX = (const float4*)(wsf + OFF_WAX/4);
    const float4* WBX = (const float4*)(wsf + OFF_WBX/4);
    const float*  CBX = wsf + OFF_CBX/4;
    const int tid = threadIdx.x;
    const int o = tid & 63;
    const int n = blockIdx.x*4 + (tid >> 6);
    float x = xyz[n], y = xyz[NPT+n], z = xyz[2*NPT+n];
    float4 A = WAX[o], B = WBX[o];
    G[(size_t)n*128 + o]  = fmaf(x, A.x, fmaf(y, A.y, z*A.z));
    T2[(size_t)n*128 + o] = fmaf(x, B.x, fmaf(y, B.y, fmaf(z, B.z, CBX[o])));
}

// ---------------- kernel 7: gather + max-pool + f1/f2 + partials ----------------
__global__ __launch_bounds__(256) void kgather(const float* __restrict__ wsf,
                                               const unsigned* __restrict__ knn,
                                               const float* __restrict__ G,
                                               const float* __restrict__ T2,
                                               const float* __restrict__ wd1,
                                               const float* __restrict__ wd2,
                                               float* __restrict__ F, float* __restrict__ F1,
                                               float* __restrict__ F2, float* __restrict__ SPm,
                                               float* __restrict__ PART)
{
    __shared__ float fsh[64][136];
    __shared__ float w1s[16][136];
    __shared__ float w2s[16][136];
    __shared__ float f1sh[64][16];
    __shared__ float f2p[64][4];
    const int tid = threadIdx.x;
    for (int i = tid; i < 2048; i += 256) {
        int o = i >> 7, cc = i & 127;
        w1s[o][cc] = wd1[i];
        w2s[o][cc] = wd2[i];
    }
    const int nl = tid >> 2, qt = tid & 3;
    const int n = blockIdx.x*64 + nl;
    const unsigned* ip = knn + (size_t)n*20;
    float acc[32];
#pragma unroll
    for (int e = 0; e < 32; ++e) acc[e] = NEG_INF;
    for (int k = 0; k < 20; ++k) {
        unsigned j = ip[k];
        const float4* g4 = (const float4*)(G + (size_t)j*128 + qt*32);
#pragma unroll
        for (int r = 0; r < 8; ++r) {
            float4 gv = g4[r];
            acc[r*4+0] = fmaxf(acc[r*4+0], gv.x);
            acc[r*4+1] = fmaxf(acc[r*4+1], gv.y);
            acc[r*4+2] = fmaxf(acc[r*4+2], gv.z);
            acc[r*4+3] = fmaxf(acc[r*4+3], gv.w);
        }
    }
    const float4* t4 = (const float4*)(T2 + (size_t)n*128 + qt*32);
    float4* fg = (float4*)(F + (size_t)n*128 + qt*32);
    float4* fs = (float4*)&fsh[nl][qt*32];
#pragma unroll
    for (int r = 0; r < 8; ++r) {
        float4 tv = t4[r];
        float4 o4;
        o4.x = fmaxf(acc[r*4+0] + tv.x, 0.f);
        o4.y = fmaxf(acc[r*4+1] + tv.y, 0.f);
        o4.z = fmaxf(acc[r*4+2] + tv.z, 0.f);
        o4.w = fmaxf(acc[r*4+3] + tv.w, 0.f);
        fg[r] = o4; fs[r] = o4;
    }
    __syncthreads();
    // phase 2: f1/f2 (4 outputs each per thread)
    float a1[4] = {0,0,0,0}, a2[4] = {0,0,0,0};
    const int ob = qt*4;
    for (int c4 = 0; c4 < 32; ++c4) {
        float4 fv = ((const float4*)&fsh[nl][0])[c4];
#pragma unroll
        for (int r = 0; r < 4; ++r) {
            float4 wv1 = ((const float4*)&w1s[ob + r][0])[c4];
            float4 wv2 = ((const float4*)&w2s[ob + r][0])[c4];
            a1[r] = fmaf(fv.x, wv1.x, fmaf(fv.y, wv1.y, fmaf(fv.z, wv1.z, fmaf(fv.w, wv1.w, a1[r]))));
            a2[r] = fmaf(fv.x, wv2.x, fmaf(fv.y, wv2.y, fmaf(fv.z, wv2.z, fmaf(fv.w, wv2.w, a2[r]))));
        }
    }
    float s2sum = 0.f;
#pragma unroll
    for (int r = 0; r < 4; ++r) {
        a1[r] = fmaxf(a1[r], 0.f);
        a2[r] = fmaxf(a2[r], 0.f);
        s2sum += a2[r];
        F1[(size_t)n*16 + ob + r] = a1[r];
        F2[(size_t)n*16 + ob + r] = a2[r];
        f1sh[nl][ob + r] = a1[r];
    }
    f2p[nl][qt] = s2sum;
    __syncthreads();
    if (qt == 0)
        SPm[n] = (f2p[nl][0] + f2p[nl][1] + f2p[nl][2] + f2p[nl][3]) * (1.0f/16.0f);
    if (tid < 16) {
        float s = 0.f;
        for (int r = 0; r < 64; ++r) s += f1sh[r][tid];
        PART[blockIdx.x*16 + tid] = s;
    }
}

// ---------------- kernel 8: reduce channel mean ----------------
__global__ __launch_bounds__(64) void kch(const float* __restrict__ PART, float* __restrict__ CH)
{
    const int tid = threadIdx.x;
    if (tid < 16) {
        float s = 0.f;
        for (int b = 0; b < 256; ++b) s += PART[b*16 + tid];
        CH[tid] = s * (1.0f/16384.0f);
    }
}

// ---------------- kernel 9: final head + mish + transpose ----------------
__global__ __launch_bounds__(64) void kfinal(const float* __restrict__ wsf,
                                             const float* __restrict__ F,
                                             const float* __restrict__ F1,
                                             const float* __restrict__ F2,
                                             const float* __restrict__ SPm,
                                             const float* __restrict__ CH,
                                             float* __restrict__ out)
{
    const float* WUP = wsf + OFF_WUP/4;
    const float* BUP = wsf + OFF_BUP/4;
    const int n = blockIdx.x*64 + threadIdx.x;
    float spv = SPm[n];
    float fin[16];
    const float4* f14 = (const float4*)(F1 + (size_t)n*16);
    const float4* f24 = (const float4*)(F2 + (size_t)n*16);
#pragma unroll
    for (int c4 = 0; c4 < 4; ++c4) {
        float4 a = f14[c4], b = f24[c4];
        fin[c4*4+0] = sqrtf(fmaf(CH[c4*4+0], spv, 1e-12f)) + a.x + b.x;
        fin[c4*4+1] = sqrtf(fmaf(CH[c4*4+1], spv, 1e-12f)) + a.y + b.y;
        fin[c4*4+2] = sqrtf(fmaf(CH[c4*4+2], spv, 1e-12f)) + a.z + b.z;
        fin[c4*4+3] = sqrtf(fmaf(CH[c4*4+3], spv, 1e-12f)) + a.w + b.w;
    }
    const float4* fF = (const float4*)(F + (size_t)n*128);
    for (int o4 = 0; o4 < 32; ++o4) {
        float4 fv = fF[o4];
        float fa[4] = {fv.x, fv.y, fv.z, fv.w};
#pragma unroll
        for (int e = 0; e < 4; ++e) {
            int o = o4*4 + e;
            float u = BUP[o];
#pragma unroll
            for (int c = 0; c < 16; ++c) u = fmaf(fin[c], WUP[o*16 + c], u);
            u = fmaxf(u, 0.f);
            float fl = fa[e] - u;
            // mish: fl * tanh(softplus(fl)) ; tanh(log1p(e^x)) = ((1+e^x)^2-1)/((1+e^x)^2+1)
            float flc = fminf(fl, 15.f);
            float t = expf(flc);
            float w = 1.f + t;
            float w2 = w*w;
            float th = (w2 - 1.f) / (w2 + 1.f);
            float res = (fl > 15.f) ? fl : fl * th;
            out[(size_t)o*NPT + n] = res;
        }
    }
}

extern "C" void kernel_launch(void* const* d_in, const int* in_sizes, int n_in,
                              void* d_out, int out_size, void* d_ws, size_t ws_size,
                              hipStream_t stream) {
    const float* xyz  = (const float*)d_in[0];
    const float* feat = (const float*)d_in[1];
    const float* w1   = (const float*)d_in[2];
    const float* b1   = (const float*)d_in[3];
    const float* g1   = (const float*)d_in[4];
    const float* bb1  = (const float*)d_in[5];
    const float* m1   = (const float*)d_in[6];
    const float* v1   = (const float*)d_in[7];
    const float* w2   = (const float*)d_in[8];
    const float* b2   = (const float*)d_in[9];
    const float* g2   = (const float*)d_in[10];
    const float* bb2  = (const float*)d_in[11];
    const float* m2   = (const float*)d_in[12];
    const float* v2   = (const float*)d_in[13];
    const float* wd1  = (const float*)d_in[14];
    const float* wd2  = (const float*)d_in[15];
    const float* wup  = (const float*)d_in[16];
    const float* bup  = (const float*)d_in[17];
    const float* gu   = (const float*)d_in[18];
    const float* bu2  = (const float*)d_in[19];
    const float* mu   = (const float*)d_in[20];
    const float* vu   = (const float*)d_in[21];
    float* out = (float*)d_out;

    float* wsf = (float*)d_ws;
    unsigned short* push = (unsigned short*)((char*)d_ws + OFF_R);
    unsigned char* cnt  = (unsigned char*)((char*)d_ws + OFF_CNT);
    unsigned* knn  = (unsigned*)((char*)d_ws + OFF_KNN);
    float* TAU  = (float*)((char*)d_ws + OFF_TAU);
    float* PART = (float*)((char*)d_ws + OFF_PART);
    float* CH   = (float*)((char*)d_ws + OFF_CH);
    // region R reused after ksel
    float* G  = (float*)((char*)d_ws + OFF_R);
    float* T2 = G  + 2097152;
    float* F  = T2 + 2097152;
    float* F1 = F  + 2097152;
    float* F2 = F1 + 262144;
    float* SPm = F2 + 262144;

    kprep<<<dim3(65),  dim3(256), 0, stream>>>(xyz, w1,b1,g1,bb1,m1,v1,
                                               w2,b2,g2,bb2,m2,v2,
                                               wup,bup,gu,bu2,mu,vu, wsf);
    ktau <<<dim3(512), dim3(256), 0, stream>>>(wsf, TAU);
    kpush<<<dim3(1024), dim3(256), 0, stream>>>(wsf, TAU, push, cnt);
    ksel <<<dim3(4096), dim3(256), 0, stream>>>(wsf, push, cnt, knn);
    kgemm<<<dim3(256), dim3(128), 0, stream>>>(feat, wsf, G, T2);
    kxpart<<<dim3(4096), dim3(256), 0, stream>>>(xyz, wsf, G, T2);
    kgather<<<dim3(256), dim3(256), 0, stream>>>(wsf, knn, G, T2, wd1, wd2, F, F1, F2, SPm, PART);
    kch  <<<dim3(1),   dim3(64), 0, stream>>>(PART, CH);
    kfinal<<<dim3(256), dim3(64), 0, stream>>>(wsf, F, F1, F2, SPm, CH, out);
}

// Round 9
// 297.487 us; speedup vs baseline: 1.0679x; 1.0679x over previous
//
#include <hip/hip_runtime.h>

#define NPT 16384
#define NEG_INF (-3.402823466e38f)

// ---- workspace byte offsets ----
#define OFF_PTS4  0u            // 16384 * 16          = 262144
#define OFF_WKC   262144u       // 128*128*4           = 65536
#define OFF_WAX   327680u       // 64*4*4              = 1024
#define OFF_WBX   328704u       // 1024
#define OFF_CBX   329728u       // 256
#define OFF_CBF   329984u       // 256
#define OFF_WUP   330240u       // 128*16*4            = 8192
#define OFF_BUP   338432u       // 512
#define OFF_TAU   338944u       // 16384*4             = 65536
#define OFF_KNN   666624u       // 16384*20*4          = 1310720
#define OFF_PART  1977344u      // 256*16*4            = 16384
#define OFF_CH    1993728u      // 256
#define OFF_R     1994240u      // reused: survivor bitmap u32[16384][512] = 33554432
                                // after ksel: G(8MB), T2(8MB), F(8MB), F1(1MB), F2(1MB), SP(64KB)

__device__ __forceinline__ float pd_score(float qx2, float qy2, float qz2, float4 c) {
    // fast screening score = 2*dot(q,c) - |c|^2 (query-constant -|q|^2 dropped; same ranking)
    return fmaf(qx2, c.x, fmaf(qy2, c.y, fmaf(qz2, c.z, -c.w)));
}

__device__ __forceinline__ unsigned sortable_f(float v) {
    unsigned b = __float_as_uint(v);
    return (b & 0x80000000u) ? ~b : (b | 0x80000000u);
}

// ---------------- kernel 1: weight folds + pts4 ----------------
__global__ __launch_bounds__(256) void kprep(
    const float* __restrict__ xyz,
    const float* __restrict__ w1, const float* __restrict__ b1,
    const float* __restrict__ g1, const float* __restrict__ bb1,
    const float* __restrict__ m1, const float* __restrict__ v1,
    const float* __restrict__ w2, const float* __restrict__ b2,
    const float* __restrict__ g2, const float* __restrict__ bb2,
    const float* __restrict__ m2, const float* __restrict__ v2,
    const float* __restrict__ wup, const float* __restrict__ bup,
    const float* __restrict__ gu, const float* __restrict__ bu2,
    const float* __restrict__ mu, const float* __restrict__ vu,
    float* __restrict__ wsf)
{
    const int tid = threadIdx.x;
    if (blockIdx.x == 0) {
        float* WKC = wsf + OFF_WKC/4;
        float* WAX = wsf + OFF_WAX/4;
        float* WBX = wsf + OFF_WBX/4;
        float* CBX = wsf + OFF_CBX/4;
        float* CBF = wsf + OFF_CBF/4;
        float* WUP = wsf + OFF_WUP/4;
        float* BUP = wsf + OFF_BUP/4;
        for (int i = tid; i < 16384; i += 256) {
            int c = i >> 7, o = i & 127, oo = o & 63;
            float s2 = g2[oo] * rsqrtf(v2[oo] + 1e-5f);
            float val = (o < 64) ? s2 * w2[oo*256 + c]
                                 : s2 * (w2[oo*256 + 128 + c] - w2[oo*256 + c]);
            WKC[c*128 + o] = val;
        }
        if (tid < 64) {
            int o = tid;
            float s1 = g1[o] * rsqrtf(v1[o] + 1e-5f);
            WAX[o*4+0] = s1 * w1[o*6+0];
            WAX[o*4+1] = s1 * w1[o*6+1];
            WAX[o*4+2] = s1 * w1[o*6+2];
            WAX[o*4+3] = 0.f;
            WBX[o*4+0] = s1 * (w1[o*6+3] - w1[o*6+0]);
            WBX[o*4+1] = s1 * (w1[o*6+4] - w1[o*6+1]);
            WBX[o*4+2] = s1 * (w1[o*6+5] - w1[o*6+2]);
            WBX[o*4+3] = 0.f;
            CBX[o] = s1 * b1[o] + (bb1[o] - m1[o]*s1);
            float s2b = g2[o] * rsqrtf(v2[o] + 1e-5f);
            CBF[o] = s2b * b2[o] + (bb2[o] - m2[o]*s2b);
        }
        if (tid < 128) {
            int o = tid;
            float su = gu[o] * rsqrtf(vu[o] + 1e-5f);
            for (int c = 0; c < 16; ++c) WUP[o*16+c] = su * wup[o*16+c];
            BUP[o] = su * bup[o] + (bu2[o] - mu[o]*su);
        }
    } else {
        // np-f32-exact |p|^2: ((x*x + y*y) + z*z), no FMA contraction, matching
        // np.sum(xyz*xyz, axis=1) sequential f32 reduction.
        #pragma clang fp contract(off)
        int n = (blockIdx.x - 1)*256 + tid;
        float x = xyz[n], y = xyz[NPT+n], z = xyz[2*NPT+n];
        float4 p; p.x = x; p.y = y; p.z = z;
        p.w = (x*x + y*y) + z*z;
        ((float4*)(wsf + OFF_PTS4/4))[n] = p;
    }
}

// ---------------- kernel 2: per-query threshold tau ----------------
// tau[q] = (20th-largest of union(8 per-thread top-6) over candidates [0,1024)) - margin.
// union-20th <= subset-20th <= full-20th, and the 5e-4 margin covers all screening-score
// vs np-f32-pd discrepancies (<= ~3e-5) -> bitmap survivors are a superset of np's top-20.
__global__ __launch_bounds__(256) void ktau(const float* __restrict__ wsf, float* __restrict__ tau)
{
    const float4* pts4 = (const float4*)(wsf + OFF_PTS4/4);
    __shared__ float4 sp[1024];
    __shared__ float t6[32][8][6];
    const int tid = threadIdx.x;
    for (int i = tid; i < 1024; i += 256) sp[i] = pts4[i];
    __syncthreads();
    const int ql = tid >> 3, t = tid & 7;
    const int q = blockIdx.x*32 + ql;
    float4 qp = pts4[q];
    float qx2 = qp.x + qp.x, qy2 = qp.y + qp.y, qz2 = qp.z + qp.z;
    float v0 = NEG_INF, v1 = NEG_INF, v2 = NEG_INF, v3 = NEG_INF, v4 = NEG_INF, v5 = NEG_INF;
    const int jb = t*128;
    for (int i = 0; i < 128; ++i) {
        float v = pd_score(qx2, qy2, qz2, sp[jb + i]);
        float n5 = v > v5 ? (v > v4 ? v4 : v) : v5;
        float n4 = v > v4 ? (v > v3 ? v3 : v) : v4;
        float n3 = v > v3 ? (v > v2 ? v2 : v) : v3;
        float n2 = v > v2 ? (v > v1 ? v1 : v) : v2;
        float n1 = v > v1 ? (v > v0 ? v0 : v) : v1;
        float n0 = v > v0 ? v : v0;
        v0 = n0; v1 = n1; v2 = n2; v3 = n3; v4 = n4; v5 = n5;
    }
    t6[ql][t][0] = v0; t6[ql][t][1] = v1; t6[ql][t][2] = v2;
    t6[ql][t][3] = v3; t6[ql][t][4] = v4; t6[ql][t][5] = v5;
    __syncthreads();
    if (t == 0) {
        int p0=0,p1=0,p2=0,p3=0,p4=0,p5=0,p6=0,p7=0;
        float last = NEG_INF;
        for (int it = 0; it < 20; ++it) {
            float best = NEG_INF; int bl = -1;
#define CHK(L, PL) { float h = t6[ql][L][(PL) < 6 ? (PL) : 5]; if (((PL) < 6) && (h > best)) { best = h; bl = L; } }
            CHK(0,p0) CHK(1,p1) CHK(2,p2) CHK(3,p3) CHK(4,p4) CHK(5,p5) CHK(6,p6) CHK(7,p7)
#undef CHK
            p0 += (bl==0); p1 += (bl==1); p2 += (bl==2); p3 += (bl==3);
            p4 += (bl==4); p5 += (bl==5); p6 += (bl==6); p7 += (bl==7);
            last = best;
        }
        tau[q] = last - 5e-4f;   // conservative margin (covers fmaf-chain vs np-f32 rounding)
    }
}

// ---------------- kernel 3: streaming scan -> survivor BITMAP ----------------
// Round-8 post-mortem: index push-lists left 128B lines ~40B dirty -> 105MB HBM write
// traffic (the whole 106us). Bitmap form: candidate index stays wave-uniform (scalar
// s_load path, zero LDS), survivor bit built branchlessly (cmp+cndmask+or, no exec-mask
// juggling), each (q,chunk) region = 32 u32 = one 128B line written FULLY via 8 uint4
// stores -> exactly 32MB dense writes, L2-merged. No caps, no cnt, no overflow.
__global__ __launch_bounds__(256) void kpush(const float* __restrict__ wsf,
                                             const float* __restrict__ tau,
                                             unsigned* __restrict__ bm)
{
    const float4* pts4 = (const float4*)(wsf + OFF_PTS4/4);
    const int qg = blockIdx.x >> 4, c = blockIdx.x & 15;
    const int tid = threadIdx.x;
    const int jbase = c * 1024;
    const int q = qg*256 + tid;
    float4 a = pts4[q];
    float ax2 = a.x + a.x, ay2 = a.y + a.y, az2 = a.z + a.z;
    float t0 = tau[q];
    uint4* dst = (uint4*)(bm + (size_t)q*512 + c*32);
    for (int g = 0; g < 8; ++g) {
        unsigned wd[4];
#pragma unroll
        for (int u = 0; u < 4; ++u) {
            const int base = jbase + (g*4 + u)*32;
            unsigned w = 0u;
#pragma unroll
            for (int k = 0; k < 32; k += 4) {
                float4 d0 = pts4[base + k];
                float4 d1 = pts4[base + k + 1];
                float4 d2 = pts4[base + k + 2];
                float4 d3 = pts4[base + k + 3];
                float s0 = fmaf(az2, d0.z, fmaf(ay2, d0.y, ax2*d0.x));
                float s1 = fmaf(az2, d1.z, fmaf(ay2, d1.y, ax2*d1.x));
                float s2 = fmaf(az2, d2.z, fmaf(ay2, d2.y, ax2*d2.x));
                float s3 = fmaf(az2, d3.z, fmaf(ay2, d3.y, ax2*d3.x));
                w |= (s0 >= t0 + d0.w) ? (1u << k)       : 0u;
                w |= (s1 >= t0 + d1.w) ? (1u << (k + 1)) : 0u;
                w |= (s2 >= t0 + d2.w) ? (1u << (k + 2)) : 0u;
                w |= (s3 >= t0 + d3.w) ? (1u << (k + 3)) : 0u;
            }
            wd[u] = w;
        }
        uint4 o; o.x = wd[0]; o.y = wd[1]; o.z = wd[2]; o.w = wd[3];
        dst[g] = o;
    }
}

// ---------------- kernel 4: exact top-20 from bitmap, wave-per-query ----------------
// One 64-lane wave per query. Lane L owns words [L*8, L*8+8) of the query's 512-word
// bitmap row (256 candidates), read as 2 coalesced dwordx4. Set bits are ffs-walked
// (~5 survivors/lane), scored np-f32 bit-exact:
//   d = ((x*x' + y*y') + z*z');  pd = ((2f*d - xx_q) - xx_c)   [fp contract off]
// inserted into a 12-deep NAMED-register list, then 20 rounds of wave-wide shfl_xor
// max + owner-pop. Keys embed the inverted index -> unique -> exact np top_k order.
// Coverage: a lane drops a top-20 key only if >12 of the top-20 land in its 256-slot
// window (Poisson lambda=0.31, P ~ 1e-15 on this fixed data).
#define KS(A,B) V##A = (kk > V##B) ? V##B : ((kk > V##A) ? kk : V##A);
__global__ __launch_bounds__(256) void ksel(const float* __restrict__ wsf,
                                            const unsigned* __restrict__ bm,
                                            unsigned* __restrict__ knn)
{
    #pragma clang fp contract(off)
    const float4* pts4 = (const float4*)(wsf + OFF_PTS4/4);
    const int lane = threadIdx.x & 63;
    const int q = blockIdx.x*4 + (threadIdx.x >> 6);
    float4 qp = pts4[q];

    unsigned long long V0=0,V1=0,V2=0,V3=0,V4=0,V5=0,V6=0,V7=0,V8=0,V9=0,V10=0,V11=0;

    const uint4* row = (const uint4*)(bm + (size_t)q*512) + lane*2;
    uint4 a0 = row[0], a1 = row[1];
    unsigned wv[8] = {a0.x, a0.y, a0.z, a0.w, a1.x, a1.y, a1.z, a1.w};
#pragma unroll
    for (int t = 0; t < 8; ++t) {
        unsigned w = wv[t];
        const int wbase = (lane*8 + t)*32;
        while (w) {
            int b = __ffs(w) - 1; w &= w - 1;
            int j = wbase + b;
            float4 cp = pts4[j];
            float d  = (qp.x*cp.x + qp.y*cp.y) + qp.z*cp.z;
            float pd = (2.0f*d - qp.w) - cp.w;
            unsigned long long kk = ((unsigned long long)sortable_f(pd) << 14)
                                  | (unsigned long long)(16383 - j);
            if (kk > V11) {
                KS(11,10) KS(10,9) KS(9,8) KS(8,7) KS(7,6) KS(6,5)
                KS(5,4) KS(4,3) KS(3,2) KS(2,1) KS(1,0)
                V0 = (kk > V0) ? kk : V0;
            }
        }
    }

    unsigned* kout = knn + (size_t)q*20;
    for (int it = 0; it < 20; ++it) {
        unsigned long long m = V0;
#pragma unroll
        for (int off = 32; off; off >>= 1) {
            unsigned long long o = __shfl_xor(m, off, 64);
            m = (o > m) ? o : m;
        }
        if (lane == 0) kout[it] = 16383u - (unsigned)(m & 0x3FFFull);
        bool own = (V0 == m);
        V0  = own ? V1  : V0;
        V1  = own ? V2  : V1;
        V2  = own ? V3  : V2;
        V3  = own ? V4  : V3;
        V4  = own ? V5  : V4;
        V5  = own ? V6  : V5;
        V6  = own ? V7  : V6;
        V7  = own ? V8  : V7;
        V8  = own ? V9  : V8;
        V9  = own ? V10 : V9;
        V10 = own ? V11 : V10;
        V11 = own ? 0ull : V11;
    }
}

// ---------------- kernel 5: GEMM for feature part of G and T2 ----------------
// G[n][64+o] = F_n . WA_f[o]   ;  T2[n][64+o] = F_n . WB_f[o] + CB_f[o]
__global__ __launch_bounds__(128) void kgemm(const float* __restrict__ feat,
                                             const float* __restrict__ wsf,
                                             float* __restrict__ G, float* __restrict__ T2)
{
    __shared__ float As[32][64];
    __shared__ float Bs[32][128];
    const float* WKC = wsf + OFF_WKC/4;
    const float* CBF = wsf + OFF_CBF/4;
    const int tid = threadIdx.x;
    const int n0 = blockIdx.x * 64;
    const int tx = tid & 15, ty = tid >> 4;
    float acc[8][8] = {};
    for (int kc = 0; kc < 4; ++kc) {
        int c0 = kc * 32;
        for (int i = tid; i < 2048; i += 128) {
            int cl = i >> 6, nl = i & 63;
            As[cl][nl] = feat[(size_t)(c0 + cl)*NPT + n0 + nl];
        }
        for (int i = tid; i < 4096; i += 128) {
            int cl = i >> 7, ol = i & 127;
            Bs[cl][ol] = WKC[(c0 + cl)*128 + ol];
        }
        __syncthreads();
        for (int cc = 0; cc < 32; ++cc) {
            float av[8], bv[8];
#pragma unroll
            for (int r = 0; r < 8; ++r) av[r] = As[cc][ty*8 + r];
#pragma unroll
            for (int s = 0; s < 8; ++s) bv[s] = Bs[cc][tx*8 + s];
#pragma unroll
            for (int r = 0; r < 8; ++r)
#pragma unroll
                for (int s = 0; s < 8; ++s)
                    acc[r][s] = fmaf(av[r], bv[s], acc[r][s]);
        }
        __syncthreads();
    }
#pragma unroll
    for (int r = 0; r < 8; ++r) {
        int n = n0 + ty*8 + r;
        if (tx < 8) {
            float* dst = G + (size_t)n*128 + 64 + tx*8;
#pragma unroll
            for (int s = 0; s < 8; ++s) dst[s] = acc[r][s];
        } else {
            int ob = (tx - 8)*8;
            float* dst = T2 + (size_t)n*128 + 64 + ob;
#pragma unroll
            for (int s = 0; s < 8; ++s) dst[s] = acc[r][s] + CBF[ob + s];
        }
    }
}

// ---------------- kernel 6: xyz part of G and T2 ----------------
__global__ __launch_bounds__(256) void kxpart(const float* __restrict__ xyz,
                                              const float* __restrict__ wsf,
                                              float* __restrict__ G, float* __restrict__ T2)
{
    const float4* WAX = (const float4*)(wsf + OFF_WAX/4);
    const float4* WBX = (const float4*)(wsf + OFF_WBX/4);
    const float*  CBX = wsf + OFF_CBX/4;
    const int tid = threadIdx.x;
    const int o = tid & 63;
    const int n = blockIdx.x*4 + (tid >> 6);
    float x = xyz[n], y = xyz[NPT+n], z = xyz[2*NPT+n];
    float4 A = WAX[o], B = WBX[o];
    G[(size_t)n*128 + o]  = fmaf(x, A.x, fmaf(y, A.y, z*A.z));
    T2[(size_t)n*128 + o] = fmaf(x, B.x, fmaf(y, B.y, fmaf(z, B.z, CBX[o])));
}

// ---------------- kernel 7: gather + max-pool + f1/f2 + partials ----------------
__global__ __launch_bounds__(256) void kgather(const float* __restrict__ wsf,
                                               const unsigned* __restrict__ knn,
                                               const float* __restrict__ G,
                                               const float* __restrict__ T2,
                                               const float* __restrict__ wd1,
                                               const float* __restrict__ wd2,
                                               float* __restrict__ F, float* __restrict__ F1,
                                               float* __restrict__ F2, float* __restrict__ SPm,
                                               float* __restrict__ PART)
{
    __shared__ float fsh[64][136];
    __shared__ float w1s[16][136];
    __shared__ float w2s[16][136];
    __shared__ float f1sh[64][16];
    __shared__ float f2p[64][4];
    const int tid = threadIdx.x;
    for (int i = tid; i < 2048; i += 256) {
        int o = i >> 7, cc = i & 127;
        w1s[o][cc] = wd1[i];
        w2s[o][cc] = wd2[i];
    }
    const int nl = tid >> 2, qt = tid & 3;
    const int n = blockIdx.x*64 + nl;
    const unsigned* ip = knn + (size_t)n*20;
    float acc[32];
#pragma unroll
    for (int e = 0; e < 32; ++e) acc[e] = NEG_INF;
    for (int k = 0; k < 20; ++k) {
        unsigned j = ip[k];
        const float4* g4 = (const float4*)(G + (size_t)j*128 + qt*32);
#pragma unroll
        for (int r = 0; r < 8; ++r) {
            float4 gv = g4[r];
            acc[r*4+0] = fmaxf(acc[r*4+0], gv.x);
            acc[r*4+1] = fmaxf(acc[r*4+1], gv.y);
            acc[r*4+2] = fmaxf(acc[r*4+2], gv.z);
            acc[r*4+3] = fmaxf(acc[r*4+3], gv.w);
        }
    }
    const float4* t4 = (const float4*)(T2 + (size_t)n*128 + qt*32);
    float4* fg = (float4*)(F + (size_t)n*128 + qt*32);
    float4* fs = (float4*)&fsh[nl][qt*32];
#pragma unroll
    for (int r = 0; r < 8; ++r) {
        float4 tv = t4[r];
        float4 o4;
        o4.x = fmaxf(acc[r*4+0] + tv.x, 0.f);
        o4.y = fmaxf(acc[r*4+1] + tv.y, 0.f);
        o4.z = fmaxf(acc[r*4+2] + tv.z, 0.f);
        o4.w = fmaxf(acc[r*4+3] + tv.w, 0.f);
        fg[r] = o4; fs[r] = o4;
    }
    __syncthreads();
    // phase 2: f1/f2 (4 outputs each per thread)
    float a1[4] = {0,0,0,0}, a2[4] = {0,0,0,0};
    const int ob = qt*4;
    for (int c4 = 0; c4 < 32; ++c4) {
        float4 fv = ((const float4*)&fsh[nl][0])[c4];
#pragma unroll
        for (int r = 0; r < 4; ++r) {
            float4 wv1 = ((const float4*)&w1s[ob + r][0])[c4];
            float4 wv2 = ((const float4*)&w2s[ob + r][0])[c4];
            a1[r] = fmaf(fv.x, wv1.x, fmaf(fv.y, wv1.y, fmaf(fv.z, wv1.z, fmaf(fv.w, wv1.w, a1[r]))));
            a2[r] = fmaf(fv.x, wv2.x, fmaf(fv.y, wv2.y, fmaf(fv.z, wv2.z, fmaf(fv.w, wv2.w, a2[r]))));
        }
    }
    float s2sum = 0.f;
#pragma unroll
    for (int r = 0; r < 4; ++r) {
        a1[r] = fmaxf(a1[r], 0.f);
        a2[r] = fmaxf(a2[r], 0.f);
        s2sum += a2[r];
        F1[(size_t)n*16 + ob + r] = a1[r];
        F2[(size_t)n*16 + ob + r] = a2[r];
        f1sh[nl][ob + r] = a1[r];
    }
    f2p[nl][qt] = s2sum;
    __syncthreads();
    if (qt == 0)
        SPm[n] = (f2p[nl][0] + f2p[nl][1] + f2p[nl][2] + f2p[nl][3]) * (1.0f/16.0f);
    if (tid < 16) {
        float s = 0.f;
        for (int r = 0; r < 64; ++r) s += f1sh[r][tid];
        PART[blockIdx.x*16 + tid] = s;
    }
}

// ---------------- kernel 8: reduce channel mean ----------------
__global__ __launch_bounds__(64) void kch(const float* __restrict__ PART, float* __restrict__ CH)
{
    const int tid = threadIdx.x;
    if (tid < 16) {
        float s = 0.f;
        for (int b = 0; b < 256; ++b) s += PART[b*16 + tid];
        CH[tid] = s * (1.0f/16384.0f);
    }
}

// ---------------- kernel 9: final head + mish + transpose ----------------
__global__ __launch_bounds__(64) void kfinal(const float* __restrict__ wsf,
                                             const float* __restrict__ F,
                                             const float* __restrict__ F1,
                                             const float* __restrict__ F2,
                                             const float* __restrict__ SPm,
                                             const float* __restrict__ CH,
                                             float* __restrict__ out)
{
    const float* WUP = wsf + OFF_WUP/4;
    const float* BUP = wsf + OFF_BUP/4;
    const int n = blockIdx.x*64 + threadIdx.x;
    float spv = SPm[n];
    float fin[16];
    const float4* f14 = (const float4*)(F1 + (size_t)n*16);
    const float4* f24 = (const float4*)(F2 + (size_t)n*16);
#pragma unroll
    for (int c4 = 0; c4 < 4; ++c4) {
        float4 a = f14[c4], b = f24[c4];
        fin[c4*4+0] = sqrtf(fmaf(CH[c4*4+0], spv, 1e-12f)) + a.x + b.x;
        fin[c4*4+1] = sqrtf(fmaf(CH[c4*4+1], spv, 1e-12f)) + a.y + b.y;
        fin[c4*4+2] = sqrtf(fmaf(CH[c4*4+2], spv, 1e-12f)) + a.z + b.z;
        fin[c4*4+3] = sqrtf(fmaf(CH[c4*4+3], spv, 1e-12f)) + a.w + b.w;
    }
    const float4* fF = (const float4*)(F + (size_t)n*128);
    for (int o4 = 0; o4 < 32; ++o4) {
        float4 fv = fF[o4];
        float fa[4] = {fv.x, fv.y, fv.z, fv.w};
#pragma unroll
        for (int e = 0; e < 4; ++e) {
            int o = o4*4 + e;
            float u = BUP[o];
#pragma unroll
            for (int c = 0; c < 16; ++c) u = fmaf(fin[c], WUP[o*16 + c], u);
            u = fmaxf(u, 0.f);
            float fl = fa[e] - u;
            // mish: fl * tanh(softplus(fl)) ; tanh(log1p(e^x)) = ((1+e^x)^2-1)/((1+e^x)^2+1)
            float flc = fminf(fl, 15.f);
            float t = expf(flc);
            float w = 1.f + t;
            float w2 = w*w;
            float th = (w2 - 1.f) / (w2 + 1.f);
            float res = (fl > 15.f) ? fl : fl * th;
            out[(size_t)o*NPT + n] = res;
        }
    }
}

extern "C" void kernel_launch(void* const* d_in, const int* in_sizes, int n_in,
                              void* d_out, int out_size, void* d_ws, size_t ws_size,
                              hipStream_t stream) {
    const float* xyz  = (const float*)d_in[0];
    const float* feat = (const float*)d_in[1];
    const float* w1   = (const float*)d_in[2];
    const float* b1   = (const float*)d_in[3];
    const float* g1   = (const float*)d_in[4];
    const float* bb1  = (const float*)d_in[5];
    const float* m1   = (const float*)d_in[6];
    const float* v1   = (const float*)d_in[7];
    const float* w2   = (const float*)d_in[8];
    const float* b2   = (const float*)d_in[9];
    const float* g2   = (const float*)d_in[10];
    const float* bb2  = (const float*)d_in[11];
    const float* m2   = (const float*)d_in[12];
    const float* v2   = (const float*)d_in[13];
    const float* wd1  = (const float*)d_in[14];
    const float* wd2  = (const float*)d_in[15];
    const float* wup  = (const float*)d_in[16];
    const float* bup  = (const float*)d_in[17];
    const float* gu   = (const float*)d_in[18];
    const float* bu2  = (const float*)d_in[19];
    const float* mu   = (const float*)d_in[20];
    const float* vu   = (const float*)d_in[21];
    float* out = (float*)d_out;

    float* wsf = (float*)d_ws;
    unsigned* bm   = (unsigned*)((char*)d_ws + OFF_R);
    unsigned* knn  = (unsigned*)((char*)d_ws + OFF_KNN);
    float* TAU  = (float*)((char*)d_ws + OFF_TAU);
    float* PART = (float*)((char*)d_ws + OFF_PART);
    float* CH   = (float*)((char*)d_ws + OFF_CH);
    // region R reused after ksel
    float* G  = (float*)((char*)d_ws + OFF_R);
    float* T2 = G  + 2097152;
    float* F  = T2 + 2097152;
    float* F1 = F  + 2097152;
    float* F2 = F1 + 262144;
    float* SPm = F2 + 262144;

    kprep<<<dim3(65),  dim3(256), 0, stream>>>(xyz, w1,b1,g1,bb1,m1,v1,
                                               w2,b2,g2,bb2,m2,v2,
                                               wup,bup,gu,bu2,mu,vu, wsf);
    ktau <<<dim3(512), dim3(256), 0, stream>>>(wsf, TAU);
    kpush<<<dim3(1024), dim3(256), 0, stream>>>(wsf, TAU, bm);
    ksel <<<dim3(4096), dim3(256), 0, stream>>>(wsf, bm, knn);
    kgemm<<<dim3(256), dim3(128), 0, stream>>>(feat, wsf, G, T2);
    kxpart<<<dim3(4096), dim3(256), 0, stream>>>(xyz, wsf, G, T2);
    kgather<<<dim3(256), dim3(256), 0, stream>>>(wsf, knn, G, T2, wd1, wd2, F, F1, F2, SPm, PART);
    kch  <<<dim3(1),   dim3(64), 0, stream>>>(PART, CH);
    kfinal<<<dim3(256), dim3(64), 0, stream>>>(wsf, F, F1, F2, SPm, CH, out);
}

// Round 10
// 265.415 us; speedup vs baseline: 1.1970x; 1.1208x over previous
//
#include <hip/hip_runtime.h>

#define NPT 16384
#define NEG_INF (-3.402823466e38f)

// ---- workspace byte offsets ----
#define OFF_PTS4  0u            // 16384 * 16          = 262144
#define OFF_WKC   262144u       // 128*128*4           = 65536
#define OFF_WAX   327680u       // 64*4*4              = 1024
#define OFF_WBX   328704u       // 1024
#define OFF_CBX   329728u       // 256
#define OFF_CBF   329984u       // 256
#define OFF_WUP   330240u       // 128*16*4            = 8192
#define OFF_BUP   338432u       // 512
#define OFF_TAU   338944u       // 16384*4             = 65536
#define OFF_KNN   666624u       // 16384*20*4          = 1310720
#define OFF_PART  1977344u      // 256*16*4            = 16384
#define OFF_CH    1993728u      // 256
#define OFF_R     1994240u      // reused: survivor bitmap u32[16384][512] = 33554432
                                // after ksel: G(8MB), T2(8MB), F(8MB), F1(1MB), F2(1MB), SP(64KB)

__device__ __forceinline__ float pd_score(float qx2, float qy2, float qz2, float4 c) {
    // fast screening score = 2*dot(q,c) - |c|^2 (query-constant -|q|^2 dropped; same ranking)
    return fmaf(qx2, c.x, fmaf(qy2, c.y, fmaf(qz2, c.z, -c.w)));
}

__device__ __forceinline__ unsigned sortable_f(float v) {
    unsigned b = __float_as_uint(v);
    return (b & 0x80000000u) ? ~b : (b | 0x80000000u);
}

// ---------------- kernel 1: weight folds + pts4 ----------------
__global__ __launch_bounds__(256) void kprep(
    const float* __restrict__ xyz,
    const float* __restrict__ w1, const float* __restrict__ b1,
    const float* __restrict__ g1, const float* __restrict__ bb1,
    const float* __restrict__ m1, const float* __restrict__ v1,
    const float* __restrict__ w2, const float* __restrict__ b2,
    const float* __restrict__ g2, const float* __restrict__ bb2,
    const float* __restrict__ m2, const float* __restrict__ v2,
    const float* __restrict__ wup, const float* __restrict__ bup,
    const float* __restrict__ gu, const float* __restrict__ bu2,
    const float* __restrict__ mu, const float* __restrict__ vu,
    float* __restrict__ wsf)
{
    const int tid = threadIdx.x;
    if (blockIdx.x == 0) {
        float* WKC = wsf + OFF_WKC/4;
        float* WAX = wsf + OFF_WAX/4;
        float* WBX = wsf + OFF_WBX/4;
        float* CBX = wsf + OFF_CBX/4;
        float* CBF = wsf + OFF_CBF/4;
        float* WUP = wsf + OFF_WUP/4;
        float* BUP = wsf + OFF_BUP/4;
        for (int i = tid; i < 16384; i += 256) {
            int c = i >> 7, o = i & 127, oo = o & 63;
            float s2 = g2[oo] * rsqrtf(v2[oo] + 1e-5f);
            float val = (o < 64) ? s2 * w2[oo*256 + c]
                                 : s2 * (w2[oo*256 + 128 + c] - w2[oo*256 + c]);
            WKC[c*128 + o] = val;
        }
        if (tid < 64) {
            int o = tid;
            float s1 = g1[o] * rsqrtf(v1[o] + 1e-5f);
            WAX[o*4+0] = s1 * w1[o*6+0];
            WAX[o*4+1] = s1 * w1[o*6+1];
            WAX[o*4+2] = s1 * w1[o*6+2];
            WAX[o*4+3] = 0.f;
            WBX[o*4+0] = s1 * (w1[o*6+3] - w1[o*6+0]);
            WBX[o*4+1] = s1 * (w1[o*6+4] - w1[o*6+1]);
            WBX[o*4+2] = s1 * (w1[o*6+5] - w1[o*6+2]);
            WBX[o*4+3] = 0.f;
            CBX[o] = s1 * b1[o] + (bb1[o] - m1[o]*s1);
            float s2b = g2[o] * rsqrtf(v2[o] + 1e-5f);
            CBF[o] = s2b * b2[o] + (bb2[o] - m2[o]*s2b);
        }
        if (tid < 128) {
            int o = tid;
            float su = gu[o] * rsqrtf(vu[o] + 1e-5f);
            for (int c = 0; c < 16; ++c) WUP[o*16+c] = su * wup[o*16+c];
            BUP[o] = su * bup[o] + (bu2[o] - mu[o]*su);
        }
    } else {
        // np-f32-exact |p|^2: ((x*x + y*y) + z*z), no FMA contraction, matching
        // np.sum(xyz*xyz, axis=1) sequential f32 reduction.
        #pragma clang fp contract(off)
        int n = (blockIdx.x - 1)*256 + tid;
        float x = xyz[n], y = xyz[NPT+n], z = xyz[2*NPT+n];
        float4 p; p.x = x; p.y = y; p.z = z;
        p.w = (x*x + y*y) + z*z;
        ((float4*)(wsf + OFF_PTS4/4))[n] = p;
    }
}

// ---------------- kernel 2: per-query threshold tau ----------------
// tau[q] = (20th-largest of union(8 per-thread top-6) over candidates [0,1024)) - margin.
// union-20th <= subset-20th <= full-20th, and the 5e-4 margin covers all screening-score
// vs np-f32-pd discrepancies (<= ~3e-5) -> bitmap survivors are a superset of np's top-20.
__global__ __launch_bounds__(256) void ktau(const float* __restrict__ wsf, float* __restrict__ tau)
{
    const float4* pts4 = (const float4*)(wsf + OFF_PTS4/4);
    __shared__ float4 sp[1024];
    __shared__ float t6[32][8][6];
    const int tid = threadIdx.x;
    for (int i = tid; i < 1024; i += 256) sp[i] = pts4[i];
    __syncthreads();
    const int ql = tid >> 3, t = tid & 7;
    const int q = blockIdx.x*32 + ql;
    float4 qp = pts4[q];
    float qx2 = qp.x + qp.x, qy2 = qp.y + qp.y, qz2 = qp.z + qp.z;
    float v0 = NEG_INF, v1 = NEG_INF, v2 = NEG_INF, v3 = NEG_INF, v4 = NEG_INF, v5 = NEG_INF;
    const int jb = t*128;
    for (int i = 0; i < 128; ++i) {
        float v = pd_score(qx2, qy2, qz2, sp[jb + i]);
        float n5 = v > v5 ? (v > v4 ? v4 : v) : v5;
        float n4 = v > v4 ? (v > v3 ? v3 : v) : v4;
        float n3 = v > v3 ? (v > v2 ? v2 : v) : v3;
        float n2 = v > v2 ? (v > v1 ? v1 : v) : v2;
        float n1 = v > v1 ? (v > v0 ? v0 : v) : v1;
        float n0 = v > v0 ? v : v0;
        v0 = n0; v1 = n1; v2 = n2; v3 = n3; v4 = n4; v5 = n5;
    }
    t6[ql][t][0] = v0; t6[ql][t][1] = v1; t6[ql][t][2] = v2;
    t6[ql][t][3] = v3; t6[ql][t][4] = v4; t6[ql][t][5] = v5;
    __syncthreads();
    if (t == 0) {
        int p0=0,p1=0,p2=0,p3=0,p4=0,p5=0,p6=0,p7=0;
        float last = NEG_INF;
        for (int it = 0; it < 20; ++it) {
            float best = NEG_INF; int bl = -1;
#define CHK(L, PL) { float h = t6[ql][L][(PL) < 6 ? (PL) : 5]; if (((PL) < 6) && (h > best)) { best = h; bl = L; } }
            CHK(0,p0) CHK(1,p1) CHK(2,p2) CHK(3,p3) CHK(4,p4) CHK(5,p5) CHK(6,p6) CHK(7,p7)
#undef CHK
            p0 += (bl==0); p1 += (bl==1); p2 += (bl==2); p3 += (bl==3);
            p4 += (bl==4); p5 += (bl==5); p6 += (bl==6); p7 += (bl==7);
            last = best;
        }
        tau[q] = last - 5e-4f;   // conservative margin (covers fmaf-chain vs np-f32 rounding)
    }
}

// ---------------- kernel 3: streaming scan -> survivor BITMAP ----------------
// Candidate index wave-uniform (scalar s_load path, zero LDS); survivor bit built
// branchlessly; each (q,chunk) = one 128B line written fully -> 32MB dense HBM writes.
__global__ __launch_bounds__(256) void kpush(const float* __restrict__ wsf,
                                             const float* __restrict__ tau,
                                             unsigned* __restrict__ bm)
{
    const float4* pts4 = (const float4*)(wsf + OFF_PTS4/4);
    const int qg = blockIdx.x >> 4, c = blockIdx.x & 15;
    const int tid = threadIdx.x;
    const int jbase = c * 1024;
    const int q = qg*256 + tid;
    float4 a = pts4[q];
    float ax2 = a.x + a.x, ay2 = a.y + a.y, az2 = a.z + a.z;
    float t0 = tau[q];
    uint4* dst = (uint4*)(bm + (size_t)q*512 + c*32);
    for (int g = 0; g < 8; ++g) {
        unsigned wd[4];
#pragma unroll
        for (int u = 0; u < 4; ++u) {
            const int base = jbase + (g*4 + u)*32;
            unsigned w = 0u;
#pragma unroll
            for (int k = 0; k < 32; k += 4) {
                float4 d0 = pts4[base + k];
                float4 d1 = pts4[base + k + 1];
                float4 d2 = pts4[base + k + 2];
                float4 d3 = pts4[base + k + 3];
                float s0 = fmaf(az2, d0.z, fmaf(ay2, d0.y, ax2*d0.x));
                float s1 = fmaf(az2, d1.z, fmaf(ay2, d1.y, ax2*d1.x));
                float s2 = fmaf(az2, d2.z, fmaf(ay2, d2.y, ax2*d2.x));
                float s3 = fmaf(az2, d3.z, fmaf(ay2, d3.y, ax2*d3.x));
                w |= (s0 >= t0 + d0.w) ? (1u << k)       : 0u;
                w |= (s1 >= t0 + d1.w) ? (1u << (k + 1)) : 0u;
                w |= (s2 >= t0 + d2.w) ? (1u << (k + 2)) : 0u;
                w |= (s3 >= t0 + d3.w) ? (1u << (k + 3)) : 0u;
            }
            wd[u] = w;
        }
        uint4 o; o.x = wd[0]; o.y = wd[1]; o.z = wd[2]; o.w = wd[3];
        dst[g] = o;
    }
}

// ---------------- kernel 4: exact top-20 from bitmap — pool-and-rank ----------------
// Round-9 post-mortem: 20 serial wave-max rounds = ~1100 VALU/wave (the 95us wall).
// New extraction, O(1) wave reductions:
//  (1) per-lane depth-8 sorted register list from the lane's 256-candidate bitmap
//      window (np-f32 bit-exact scores, fp contract off);
//  (2) ONE bitonic sort (21 shfl stages) of the 64 lane-maxima -> theta = 20th-largest
//      lane-max (ascending sort, lane 44). theta <= 20th-largest key overall, so every
//      top-20 key is >= theta;
//  (3) prefix-sum compaction of all kept keys >= theta into an LDS pool (E[C]~24);
//  (4) each pool key's exact global rank = #greater pool keys (C broadcast LDS reads);
//      rank<20 -> knn[q*20+rank]: exact np descending top_k order incl. tie-breaks.
// Coverage: lane needs >8 of the top-20 in its window to drop one (P ~ 6e-11 * 16384).
#define KS(A,B) V##A = (kk > V##B) ? V##B : ((kk > V##A) ? kk : V##A);
__global__ __launch_bounds__(256) void ksel(const float* __restrict__ wsf,
                                            const unsigned* __restrict__ bm,
                                            unsigned* __restrict__ knn)
{
    #pragma clang fp contract(off)
    const float4* pts4 = (const float4*)(wsf + OFF_PTS4/4);
    __shared__ unsigned long long pool[4][128];
    const int lane = threadIdx.x & 63;
    const int qw   = threadIdx.x >> 6;
    const int q = blockIdx.x*4 + qw;
    float4 qp = pts4[q];

    unsigned long long V0=0,V1=0,V2=0,V3=0,V4=0,V5=0,V6=0,V7=0;

    const uint4* row = (const uint4*)(bm + (size_t)q*512) + lane*2;
    uint4 a0 = row[0], a1 = row[1];
    unsigned wv[8] = {a0.x, a0.y, a0.z, a0.w, a1.x, a1.y, a1.z, a1.w};
#pragma unroll
    for (int t = 0; t < 8; ++t) {
        unsigned w = wv[t];
        const int wbase = (lane*8 + t)*32;
        while (w) {
            int b = __ffs(w) - 1; w &= w - 1;
            int j = wbase + b;
            float4 cp = pts4[j];
            float d  = (qp.x*cp.x + qp.y*cp.y) + qp.z*cp.z;
            float pd = (2.0f*d - qp.w) - cp.w;
            unsigned long long kk = ((unsigned long long)sortable_f(pd) << 14)
                                  | (unsigned long long)(16383 - j);
            if (kk > V7) {
                KS(7,6) KS(6,5) KS(5,4) KS(4,3) KS(3,2) KS(2,1) KS(1,0)
                V0 = (kk > V0) ? kk : V0;
            }
        }
    }

    // (2) bitonic ascending sort of lane maxima; theta at lane 44 (20th largest)
    unsigned long long s = V0;
#pragma unroll
    for (int k = 2; k <= 64; k <<= 1) {
#pragma unroll
        for (int j = k >> 1; j > 0; j >>= 1) {
            unsigned long long o = __shfl_xor(s, j, 64);
            bool up = ((lane & k) == 0);
            bool lower = ((lane & j) == 0);
            s = (lower == up) ? ((s < o) ? s : o) : ((s > o) ? s : o);
        }
    }
    unsigned long long theta = __shfl(s, 44, 64);

    // (3) compact kept keys >= theta into LDS pool
    int cnt = (int)(V0 >= theta) + (int)(V1 >= theta) + (int)(V2 >= theta)
            + (int)(V3 >= theta) + (int)(V4 >= theta) + (int)(V5 >= theta)
            + (int)(V6 >= theta) + (int)(V7 >= theta);
    int sc = cnt;
#pragma unroll
    for (int o = 1; o < 64; o <<= 1) {
        int t2 = __shfl_up(sc, o, 64);
        sc += (lane >= o) ? t2 : 0;
    }
    int C = __shfl(sc, 63, 64);
    int base = sc - cnt;
    if (C > 128) C = 128;
    unsigned long long* pq = pool[qw];
#define WPOOL(I, VI) if (I < cnt) { int p = base + I; if (p < 128) pq[p] = VI; }
    WPOOL(0, V0) WPOOL(1, V1) WPOOL(2, V2) WPOOL(3, V3)
    WPOOL(4, V4) WPOOL(5, V5) WPOOL(6, V6) WPOOL(7, V7)
#undef WPOOL
    __syncthreads();

    // (4) rank by counting greater pool keys (broadcast LDS reads)
    bool h1 = lane < C;
    bool h2 = (lane + 64) < C;
    unsigned long long k1 = h1 ? pq[lane] : 0ull;
    unsigned long long k2 = h2 ? pq[lane + 64] : 0ull;
    int r1 = 0, r2 = 0;
    for (int i = 0; i < C; ++i) {
        unsigned long long ki = pq[i];
        r1 += (int)(ki > k1);
        r2 += (int)(ki > k2);
    }
    unsigned* kout = knn + (size_t)q*20;
    if (h1 && r1 < 20) kout[r1] = 16383u - (unsigned)(k1 & 0x3FFFull);
    if (h2 && r2 < 20) kout[r2] = 16383u - (unsigned)(k2 & 0x3FFFull);
}

// ---------------- kernel 5: GEMM for feature part of G and T2 ----------------
// G[n][64+o] = F_n . WA_f[o]   ;  T2[n][64+o] = F_n . WB_f[o] + CB_f[o]
__global__ __launch_bounds__(128) void kgemm(const float* __restrict__ feat,
                                             const float* __restrict__ wsf,
                                             float* __restrict__ G, float* __restrict__ T2)
{
    __shared__ float As[32][64];
    __shared__ float Bs[32][128];
    const float* WKC = wsf + OFF_WKC/4;
    const float* CBF = wsf + OFF_CBF/4;
    const int tid = threadIdx.x;
    const int n0 = blockIdx.x * 64;
    const int tx = tid & 15, ty = tid >> 4;
    float acc[8][8] = {};
    for (int kc = 0; kc < 4; ++kc) {
        int c0 = kc * 32;
        for (int i = tid; i < 2048; i += 128) {
            int cl = i >> 6, nl = i & 63;
            As[cl][nl] = feat[(size_t)(c0 + cl)*NPT + n0 + nl];
        }
        for (int i = tid; i < 4096; i += 128) {
            int cl = i >> 7, ol = i & 127;
            Bs[cl][ol] = WKC[(c0 + cl)*128 + ol];
        }
        __syncthreads();
        for (int cc = 0; cc < 32; ++cc) {
            float av[8], bv[8];
#pragma unroll
            for (int r = 0; r < 8; ++r) av[r] = As[cc][ty*8 + r];
#pragma unroll
            for (int s = 0; s < 8; ++s) bv[s] = Bs[cc][tx*8 + s];
#pragma unroll
            for (int r = 0; r < 8; ++r)
#pragma unroll
                for (int s = 0; s < 8; ++s)
                    acc[r][s] = fmaf(av[r], bv[s], acc[r][s]);
        }
        __syncthreads();
    }
#pragma unroll
    for (int r = 0; r < 8; ++r) {
        int n = n0 + ty*8 + r;
        if (tx < 8) {
            float* dst = G + (size_t)n*128 + 64 + tx*8;
#pragma unroll
            for (int s = 0; s < 8; ++s) dst[s] = acc[r][s];
        } else {
            int ob = (tx - 8)*8;
            float* dst = T2 + (size_t)n*128 + 64 + ob;
#pragma unroll
            for (int s = 0; s < 8; ++s) dst[s] = acc[r][s] + CBF[ob + s];
        }
    }
}

// ---------------- kernel 6: xyz part of G and T2 ----------------
__global__ __launch_bounds__(256) void kxpart(const float* __restrict__ xyz,
                                              const float* __restrict__ wsf,
                                              float* __restrict__ G, float* __restrict__ T2)
{
    const float4* WAX = (const float4*)(wsf + OFF_WAX/4);
    const float4* WBX = (const float4*)(wsf + OFF_WBX/4);
    const float*  CBX = wsf + OFF_CBX/4;
    const int tid = threadIdx.x;
    const int o = tid & 63;
    const int n = blockIdx.x*4 + (tid >> 6);
    float x = xyz[n], y = xyz[NPT+n], z = xyz[2*NPT+n];
    float4 A = WAX[o], B = WBX[o];
    G[(size_t)n*128 + o]  = fmaf(x, A.x, fmaf(y, A.y, z*A.z));
    T2[(size_t)n*128 + o] = fmaf(x, B.x, fmaf(y, B.y, fmaf(z, B.z, CBX[o])));
}

// ---------------- kernel 7: gather + max-pool + f1/f2 + partials ----------------
__global__ __launch_bounds__(256) void kgather(const float* __restrict__ wsf,
                                               const unsigned* __restrict__ knn,
                                               const float* __restrict__ G,
                                               const float* __restrict__ T2,
                                               const float* __restrict__ wd1,
                                               const float* __restrict__ wd2,
                                               float* __restrict__ F, float* __restrict__ F1,
                                               float* __restrict__ F2, float* __restrict__ SPm,
                                               float* __restrict__ PART)
{
    __shared__ float fsh[64][136];
    __shared__ float w1s[16][136];
    __shared__ float w2s[16][136];
    __shared__ float f1sh[64][16];
    __shared__ float f2p[64][4];
    const int tid = threadIdx.x;
    for (int i = tid; i < 2048; i += 256) {
        int o = i >> 7, cc = i & 127;
        w1s[o][cc] = wd1[i];
        w2s[o][cc] = wd2[i];
    }
    const int nl = tid >> 2, qt = tid & 3;
    const int n = blockIdx.x*64 + nl;
    const unsigned* ip = knn + (size_t)n*20;
    float acc[32];
#pragma unroll
    for (int e = 0; e < 32; ++e) acc[e] = NEG_INF;
    for (int k = 0; k < 20; ++k) {
        unsigned j = ip[k];
        const float4* g4 = (const float4*)(G + (size_t)j*128 + qt*32);
#pragma unroll
        for (int r = 0; r < 8; ++r) {
            float4 gv = g4[r];
            acc[r*4+0] = fmaxf(acc[r*4+0], gv.x);
            acc[r*4+1] = fmaxf(acc[r*4+1], gv.y);
            acc[r*4+2] = fmaxf(acc[r*4+2], gv.z);
            acc[r*4+3] = fmaxf(acc[r*4+3], gv.w);
        }
    }
    const float4* t4 = (const float4*)(T2 + (size_t)n*128 + qt*32);
    float4* fg = (float4*)(F + (size_t)n*128 + qt*32);
    float4* fs = (float4*)&fsh[nl][qt*32];
#pragma unroll
    for (int r = 0; r < 8; ++r) {
        float4 tv = t4[r];
        float4 o4;
        o4.x = fmaxf(acc[r*4+0] + tv.x, 0.f);
        o4.y = fmaxf(acc[r*4+1] + tv.y, 0.f);
        o4.z = fmaxf(acc[r*4+2] + tv.z, 0.f);
        o4.w = fmaxf(acc[r*4+3] + tv.w, 0.f);
        fg[r] = o4; fs[r] = o4;
    }
    __syncthreads();
    // phase 2: f1/f2 (4 outputs each per thread)
    float a1[4] = {0,0,0,0}, a2[4] = {0,0,0,0};
    const int ob = qt*4;
    for (int c4 = 0; c4 < 32; ++c4) {
        float4 fv = ((const float4*)&fsh[nl][0])[c4];
#pragma unroll
        for (int r = 0; r < 4; ++r) {
            float4 wv1 = ((const float4*)&w1s[ob + r][0])[c4];
            float4 wv2 = ((const float4*)&w2s[ob + r][0])[c4];
            a1[r] = fmaf(fv.x, wv1.x, fmaf(fv.y, wv1.y, fmaf(fv.z, wv1.z, fmaf(fv.w, wv1.w, a1[r]))));
            a2[r] = fmaf(fv.x, wv2.x, fmaf(fv.y, wv2.y, fmaf(fv.z, wv2.z, fmaf(fv.w, wv2.w, a2[r]))));
        }
    }
    float s2sum = 0.f;
#pragma unroll
    for (int r = 0; r < 4; ++r) {
        a1[r] = fmaxf(a1[r], 0.f);
        a2[r] = fmaxf(a2[r], 0.f);
        s2sum += a2[r];
        F1[(size_t)n*16 + ob + r] = a1[r];
        F2[(size_t)n*16 + ob + r] = a2[r];
        f1sh[nl][ob + r] = a1[r];
    }
    f2p[nl][qt] = s2sum;
    __syncthreads();
    if (qt == 0)
        SPm[n] = (f2p[nl][0] + f2p[nl][1] + f2p[nl][2] + f2p[nl][3]) * (1.0f/16.0f);
    if (tid < 16) {
        float s = 0.f;
        for (int r = 0; r < 64; ++r) s += f1sh[r][tid];
        PART[blockIdx.x*16 + tid] = s;
    }
}

// ---------------- kernel 8: reduce channel mean ----------------
__global__ __launch_bounds__(64) void kch(const float* __restrict__ PART, float* __restrict__ CH)
{
    const int tid = threadIdx.x;
    if (tid < 16) {
        float s = 0.f;
        for (int b = 0; b < 256; ++b) s += PART[b*16 + tid];
        CH[tid] = s * (1.0f/16384.0f);
    }
}

// ---------------- kernel 9: final head + mish + transpose ----------------
__global__ __launch_bounds__(64) void kfinal(const float* __restrict__ wsf,
                                             const float* __restrict__ F,
                                             const float* __restrict__ F1,
                                             const float* __restrict__ F2,
                                             const float* __restrict__ SPm,
                                             const float* __restrict__ CH,
                                             float* __restrict__ out)
{
    const float* WUP = wsf + OFF_WUP/4;
    const float* BUP = wsf + OFF_BUP/4;
    const int n = blockIdx.x*64 + threadIdx.x;
    float spv = SPm[n];
    float fin[16];
    const float4* f14 = (const float4*)(F1 + (size_t)n*16);
    const float4* f24 = (const float4*)(F2 + (size_t)n*16);
#pragma unroll
    for (int c4 = 0; c4 < 4; ++c4) {
        float4 a = f14[c4], b = f24[c4];
        fin[c4*4+0] = sqrtf(fmaf(CH[c4*4+0], spv, 1e-12f)) + a.x + b.x;
        fin[c4*4+1] = sqrtf(fmaf(CH[c4*4+1], spv, 1e-12f)) + a.y + b.y;
        fin[c4*4+2] = sqrtf(fmaf(CH[c4*4+2], spv, 1e-12f)) + a.z + b.z;
        fin[c4*4+3] = sqrtf(fmaf(CH[c4*4+3], spv, 1e-12f)) + a.w + b.w;
    }
    const float4* fF = (const float4*)(F + (size_t)n*128);
    for (int o4 = 0; o4 < 32; ++o4) {
        float4 fv = fF[o4];
        float fa[4] = {fv.x, fv.y, fv.z, fv.w};
#pragma unroll
        for (int e = 0; e < 4; ++e) {
            int o = o4*4 + e;
            float u = BUP[o];
#pragma unroll
            for (int c = 0; c < 16; ++c) u = fmaf(fin[c], WUP[o*16 + c], u);
            u = fmaxf(u, 0.f);
            float fl = fa[e] - u;
            // mish: fl * tanh(softplus(fl)) ; tanh(log1p(e^x)) = ((1+e^x)^2-1)/((1+e^x)^2+1)
            float flc = fminf(fl, 15.f);
            float t = expf(flc);
            float w = 1.f + t;
            float w2 = w*w;
            float th = (w2 - 1.f) / (w2 + 1.f);
            float res = (fl > 15.f) ? fl : fl * th;
            out[(size_t)o*NPT + n] = res;
        }
    }
}

extern "C" void kernel_launch(void* const* d_in, const int* in_sizes, int n_in,
                              void* d_out, int out_size, void* d_ws, size_t ws_size,
                              hipStream_t stream) {
    const float* xyz  = (const float*)d_in[0];
    const float* feat = (const float*)d_in[1];
    const float* w1   = (const float*)d_in[2];
    const float* b1   = (const float*)d_in[3];
    const float* g1   = (const float*)d_in[4];
    const float* bb1  = (const float*)d_in[5];
    const float* m1   = (const float*)d_in[6];
    const float* v1   = (const float*)d_in[7];
    const float* w2   = (const float*)d_in[8];
    const float* b2   = (const float*)d_in[9];
    const float* g2   = (const float*)d_in[10];
    const float* bb2  = (const float*)d_in[11];
    const float* m2   = (const float*)d_in[12];
    const float* v2   = (const float*)d_in[13];
    const float* wd1  = (const float*)d_in[14];
    const float* wd2  = (const float*)d_in[15];
    const float* wup  = (const float*)d_in[16];
    const float* bup  = (const float*)d_in[17];
    const float* gu   = (const float*)d_in[18];
    const float* bu2  = (const float*)d_in[19];
    const float* mu   = (const float*)d_in[20];
    const float* vu   = (const float*)d_in[21];
    float* out = (float*)d_out;

    float* wsf = (float*)d_ws;
    unsigned* bm   = (unsigned*)((char*)d_ws + OFF_R);
    unsigned* knn  = (unsigned*)((char*)d_ws + OFF_KNN);
    float* TAU  = (float*)((char*)d_ws + OFF_TAU);
    float* PART = (float*)((char*)d_ws + OFF_PART);
    float* CH   = (float*)((char*)d_ws + OFF_CH);
    // region R reused after ksel
    float* G  = (float*)((char*)d_ws + OFF_R);
    float* T2 = G  + 2097152;
    float* F  = T2 + 2097152;
    float* F1 = F  + 2097152;
    float* F2 = F1 + 262144;
    float* SPm = F2 + 262144;

    kprep<<<dim3(65),  dim3(256), 0, stream>>>(xyz, w1,b1,g1,bb1,m1,v1,
                                               w2,b2,g2,bb2,m2,v2,
                                               wup,bup,gu,bu2,mu,vu, wsf);
    ktau <<<dim3(512), dim3(256), 0, stream>>>(wsf, TAU);
    kpush<<<dim3(1024), dim3(256), 0, stream>>>(wsf, TAU, bm);
    ksel <<<dim3(4096), dim3(256), 0, stream>>>(wsf, bm, knn);
    kgemm<<<dim3(256), dim3(128), 0, stream>>>(feat, wsf, G, T2);
    kxpart<<<dim3(4096), dim3(256), 0, stream>>>(xyz, wsf, G, T2);
    kgather<<<dim3(256), dim3(256), 0, stream>>>(wsf, knn, G, T2, wd1, wd2, F, F1, F2, SPm, PART);
    kch  <<<dim3(1),   dim3(64), 0, stream>>>(PART, CH);
    kfinal<<<dim3(256), dim3(64), 0, stream>>>(wsf, F, F1, F2, SPm, CH, out);
}

// Round 11
// 263.163 us; speedup vs baseline: 1.2072x; 1.0086x over previous
//
#include <hip/hip_runtime.h>

#define NPT 16384
#define NEG_INF (-3.402823466e38f)

// ---- workspace byte offsets ----
#define OFF_PTS4  0u            // 16384 * 16          = 262144
#define OFF_WKC   262144u       // 128*128*4           = 65536
#define OFF_WAX   327680u       // 64*4*4              = 1024
#define OFF_WBX   328704u       // 1024
#define OFF_CBX   329728u       // 256
#define OFF_CBF   329984u       // 256
#define OFF_WUP   330240u       // 128*16*4            = 8192
#define OFF_BUP   338432u       // 512
#define OFF_TAU   338944u       // 16384*4             = 65536
#define OFF_KNN   666624u       // 16384*20*4          = 1310720
#define OFF_PART  1977344u      // 256*16*4            = 16384
#define OFF_CH    1993728u      // 256
#define OFF_R     1994240u      // reused: survivor bitmap u32[16384][512] = 33554432
                                // after ksel: G(8MB), T2(8MB), F(8MB), F1(1MB), F2(1MB), SP(64KB)

__device__ __forceinline__ float pd_score(float qx2, float qy2, float qz2, float4 c) {
    // fast screening score = 2*dot(q,c) - |c|^2 (query-constant -|q|^2 dropped; same ranking)
    return fmaf(qx2, c.x, fmaf(qy2, c.y, fmaf(qz2, c.z, -c.w)));
}

__device__ __forceinline__ unsigned sortable_f(float v) {
    unsigned b = __float_as_uint(v);
    return (b & 0x80000000u) ? ~b : (b | 0x80000000u);
}

// ---------------- kernel 1: weight folds + pts4 ----------------
__global__ __launch_bounds__(256) void kprep(
    const float* __restrict__ xyz,
    const float* __restrict__ w1, const float* __restrict__ b1,
    const float* __restrict__ g1, const float* __restrict__ bb1,
    const float* __restrict__ m1, const float* __restrict__ v1,
    const float* __restrict__ w2, const float* __restrict__ b2,
    const float* __restrict__ g2, const float* __restrict__ bb2,
    const float* __restrict__ m2, const float* __restrict__ v2,
    const float* __restrict__ wup, const float* __restrict__ bup,
    const float* __restrict__ gu, const float* __restrict__ bu2,
    const float* __restrict__ mu, const float* __restrict__ vu,
    float* __restrict__ wsf)
{
    const int tid = threadIdx.x;
    if (blockIdx.x == 0) {
        float* WKC = wsf + OFF_WKC/4;
        float* WAX = wsf + OFF_WAX/4;
        float* WBX = wsf + OFF_WBX/4;
        float* CBX = wsf + OFF_CBX/4;
        float* CBF = wsf + OFF_CBF/4;
        float* WUP = wsf + OFF_WUP/4;
        float* BUP = wsf + OFF_BUP/4;
        for (int i = tid; i < 16384; i += 256) {
            int c = i >> 7, o = i & 127, oo = o & 63;
            float s2 = g2[oo] * rsqrtf(v2[oo] + 1e-5f);
            float val = (o < 64) ? s2 * w2[oo*256 + c]
                                 : s2 * (w2[oo*256 + 128 + c] - w2[oo*256 + c]);
            WKC[c*128 + o] = val;
        }
        if (tid < 64) {
            int o = tid;
            float s1 = g1[o] * rsqrtf(v1[o] + 1e-5f);
            WAX[o*4+0] = s1 * w1[o*6+0];
            WAX[o*4+1] = s1 * w1[o*6+1];
            WAX[o*4+2] = s1 * w1[o*6+2];
            WAX[o*4+3] = 0.f;
            WBX[o*4+0] = s1 * (w1[o*6+3] - w1[o*6+0]);
            WBX[o*4+1] = s1 * (w1[o*6+4] - w1[o*6+1]);
            WBX[o*4+2] = s1 * (w1[o*6+5] - w1[o*6+2]);
            WBX[o*4+3] = 0.f;
            CBX[o] = s1 * b1[o] + (bb1[o] - m1[o]*s1);
            float s2b = g2[o] * rsqrtf(v2[o] + 1e-5f);
            CBF[o] = s2b * b2[o] + (bb2[o] - m2[o]*s2b);
        }
        if (tid < 128) {
            int o = tid;
            float su = gu[o] * rsqrtf(vu[o] + 1e-5f);
            for (int c = 0; c < 16; ++c) WUP[o*16+c] = su * wup[o*16+c];
            BUP[o] = su * bup[o] + (bu2[o] - mu[o]*su);
        }
    } else {
        // np-f32-exact |p|^2: ((x*x + y*y) + z*z), no FMA contraction, matching
        // np.sum(xyz*xyz, axis=1) sequential f32 reduction.
        #pragma clang fp contract(off)
        int n = (blockIdx.x - 1)*256 + tid;
        float x = xyz[n], y = xyz[NPT+n], z = xyz[2*NPT+n];
        float4 p; p.x = x; p.y = y; p.z = z;
        p.w = (x*x + y*y) + z*z;
        ((float4*)(wsf + OFF_PTS4/4))[n] = p;
    }
}

// ---------------- kernel 2: per-query threshold tau ----------------
// tau[q] = (20th-largest of union(8 per-thread top-6) over candidates [0,1024)) - margin.
// union-20th <= subset-20th <= full-20th, and the 5e-4 margin covers all screening-score
// vs np-f32-pd discrepancies (<= ~3e-5) -> bitmap survivors are a superset of np's top-20.
__global__ __launch_bounds__(256) void ktau(const float* __restrict__ wsf, float* __restrict__ tau)
{
    const float4* pts4 = (const float4*)(wsf + OFF_PTS4/4);
    __shared__ float4 sp[1024];
    __shared__ float t6[32][8][6];
    const int tid = threadIdx.x;
    for (int i = tid; i < 1024; i += 256) sp[i] = pts4[i];
    __syncthreads();
    const int ql = tid >> 3, t = tid & 7;
    const int q = blockIdx.x*32 + ql;
    float4 qp = pts4[q];
    float qx2 = qp.x + qp.x, qy2 = qp.y + qp.y, qz2 = qp.z + qp.z;
    float v0 = NEG_INF, v1 = NEG_INF, v2 = NEG_INF, v3 = NEG_INF, v4 = NEG_INF, v5 = NEG_INF;
    const int jb = t*128;
    for (int i = 0; i < 128; ++i) {
        float v = pd_score(qx2, qy2, qz2, sp[jb + i]);
        float n5 = v > v5 ? (v > v4 ? v4 : v) : v5;
        float n4 = v > v4 ? (v > v3 ? v3 : v) : v4;
        float n3 = v > v3 ? (v > v2 ? v2 : v) : v3;
        float n2 = v > v2 ? (v > v1 ? v1 : v) : v2;
        float n1 = v > v1 ? (v > v0 ? v0 : v) : v1;
        float n0 = v > v0 ? v : v0;
        v0 = n0; v1 = n1; v2 = n2; v3 = n3; v4 = n4; v5 = n5;
    }
    t6[ql][t][0] = v0; t6[ql][t][1] = v1; t6[ql][t][2] = v2;
    t6[ql][t][3] = v3; t6[ql][t][4] = v4; t6[ql][t][5] = v5;
    __syncthreads();
    if (t == 0) {
        int p0=0,p1=0,p2=0,p3=0,p4=0,p5=0,p6=0,p7=0;
        float last = NEG_INF;
        for (int it = 0; it < 20; ++it) {
            float best = NEG_INF; int bl = -1;
#define CHK(L, PL) { float h = t6[ql][L][(PL) < 6 ? (PL) : 5]; if (((PL) < 6) && (h > best)) { best = h; bl = L; } }
            CHK(0,p0) CHK(1,p1) CHK(2,p2) CHK(3,p3) CHK(4,p4) CHK(5,p5) CHK(6,p6) CHK(7,p7)
#undef CHK
            p0 += (bl==0); p1 += (bl==1); p2 += (bl==2); p3 += (bl==3);
            p4 += (bl==4); p5 += (bl==5); p6 += (bl==6); p7 += (bl==7);
            last = best;
        }
        tau[q] = last - 5e-4f;   // conservative margin (covers fmaf-chain vs np-f32 rounding)
    }
}

// ---------------- kernel 3: streaming scan -> survivor BITMAP ----------------
// Round-10 post-mortem: the 8 uint4 stores per (q,chunk) line were spread across the
// g-loop (128 evals apart) -> partially-dirty 128B lines written back to HBM in 64B
// sector installments -> WRITE_SIZE 150MB vs 32MB bitmap (4.7x amplification, the
// 66us wall). Fix: stage the 8 words per thread in LDS during the scan (private slot,
// no sync; [256][9] padding breaks bank aliasing), then issue the 8 global stores
// BACK-TO-BACK at the end -> each line fully dirtied within ~8 instructions -> L2
// write-combines -> dense 32MB HBM writes. Scan itself unchanged (scalar s_load path).
__global__ __launch_bounds__(256) void kpush(const float* __restrict__ wsf,
                                             const float* __restrict__ tau,
                                             unsigned* __restrict__ bm)
{
    const float4* pts4 = (const float4*)(wsf + OFF_PTS4/4);
    __shared__ uint4 st[256][9];   // 36KB; slot [tid][g], padded (9) to spread banks
    const int qg = blockIdx.x >> 4, c = blockIdx.x & 15;
    const int tid = threadIdx.x;
    const int jbase = c * 1024;
    const int q = qg*256 + tid;
    float4 a = pts4[q];
    float ax2 = a.x + a.x, ay2 = a.y + a.y, az2 = a.z + a.z;
    float t0 = tau[q];
    for (int g = 0; g < 8; ++g) {
        unsigned wd[4];
#pragma unroll
        for (int u = 0; u < 4; ++u) {
            const int base = jbase + (g*4 + u)*32;
            unsigned w = 0u;
#pragma unroll
            for (int k = 0; k < 32; k += 4) {
                float4 d0 = pts4[base + k];
                float4 d1 = pts4[base + k + 1];
                float4 d2 = pts4[base + k + 2];
                float4 d3 = pts4[base + k + 3];
                float s0 = fmaf(az2, d0.z, fmaf(ay2, d0.y, ax2*d0.x));
                float s1 = fmaf(az2, d1.z, fmaf(ay2, d1.y, ax2*d1.x));
                float s2 = fmaf(az2, d2.z, fmaf(ay2, d2.y, ax2*d2.x));
                float s3 = fmaf(az2, d3.z, fmaf(ay2, d3.y, ax2*d3.x));
                w |= (s0 >= t0 + d0.w) ? (1u << k)       : 0u;
                w |= (s1 >= t0 + d1.w) ? (1u << (k + 1)) : 0u;
                w |= (s2 >= t0 + d2.w) ? (1u << (k + 2)) : 0u;
                w |= (s3 >= t0 + d3.w) ? (1u << (k + 3)) : 0u;
            }
            wd[u] = w;
        }
        uint4 o; o.x = wd[0]; o.y = wd[1]; o.z = wd[2]; o.w = wd[3];
        st[tid][g] = o;
    }
    // back-to-back full-line writeout (thread-private slot: no barrier needed)
    uint4* dst = (uint4*)(bm + (size_t)q*512 + c*32);
#pragma unroll
    for (int g = 0; g < 8; ++g) dst[g] = st[tid][g];
}

// ---------------- kernel 4: exact top-20 from bitmap — pool-and-rank ----------------
//  (1) per-lane depth-8 sorted register list from the lane's 256-candidate bitmap
//      window (np-f32 bit-exact scores, fp contract off);
//  (2) ONE bitonic sort (21 shfl stages) of the 64 lane-maxima -> theta = 20th-largest
//      lane-max (ascending sort, lane 44). theta <= 20th-largest key overall;
//  (3) prefix-sum compaction of all kept keys >= theta into an LDS pool (E[C]~24);
//  (4) each pool key's exact global rank = #greater pool keys (C broadcast LDS reads);
//      rank<20 -> knn[q*20+rank]: exact np descending top_k order incl. tie-breaks.
// Coverage: lane needs >8 of the top-20 in its window to drop one (P ~ 6e-11 * 16384).
#define KS(A,B) V##A = (kk > V##B) ? V##B : ((kk > V##A) ? kk : V##A);
__global__ __launch_bounds__(256) void ksel(const float* __restrict__ wsf,
                                            const unsigned* __restrict__ bm,
                                            unsigned* __restrict__ knn)
{
    #pragma clang fp contract(off)
    const float4* pts4 = (const float4*)(wsf + OFF_PTS4/4);
    __shared__ unsigned long long pool[4][128];
    const int lane = threadIdx.x & 63;
    const int qw   = threadIdx.x >> 6;
    const int q = blockIdx.x*4 + qw;
    float4 qp = pts4[q];

    unsigned long long V0=0,V1=0,V2=0,V3=0,V4=0,V5=0,V6=0,V7=0;

    const uint4* row = (const uint4*)(bm + (size_t)q*512) + lane*2;
    uint4 a0 = row[0], a1 = row[1];
    unsigned wv[8] = {a0.x, a0.y, a0.z, a0.w, a1.x, a1.y, a1.z, a1.w};
#pragma unroll
    for (int t = 0; t < 8; ++t) {
        unsigned w = wv[t];
        const int wbase = (lane*8 + t)*32;
        while (w) {
            int b = __ffs(w) - 1; w &= w - 1;
            int j = wbase + b;
            float4 cp = pts4[j];
            float d  = (qp.x*cp.x + qp.y*cp.y) + qp.z*cp.z;
            float pd = (2.0f*d - qp.w) - cp.w;
            unsigned long long kk = ((unsigned long long)sortable_f(pd) << 14)
                                  | (unsigned long long)(16383 - j);
            if (kk > V7) {
                KS(7,6) KS(6,5) KS(5,4) KS(4,3) KS(3,2) KS(2,1) KS(1,0)
                V0 = (kk > V0) ? kk : V0;
            }
        }
    }

    // (2) bitonic ascending sort of lane maxima; theta at lane 44 (20th largest)
    unsigned long long s = V0;
#pragma unroll
    for (int k = 2; k <= 64; k <<= 1) {
#pragma unroll
        for (int j = k >> 1; j > 0; j >>= 1) {
            unsigned long long o = __shfl_xor(s, j, 64);
            bool up = ((lane & k) == 0);
            bool lower = ((lane & j) == 0);
            s = (lower == up) ? ((s < o) ? s : o) : ((s > o) ? s : o);
        }
    }
    unsigned long long theta = __shfl(s, 44, 64);

    // (3) compact kept keys >= theta into LDS pool
    int cnt = (int)(V0 >= theta) + (int)(V1 >= theta) + (int)(V2 >= theta)
            + (int)(V3 >= theta) + (int)(V4 >= theta) + (int)(V5 >= theta)
            + (int)(V6 >= theta) + (int)(V7 >= theta);
    int sc = cnt;
#pragma unroll
    for (int o = 1; o < 64; o <<= 1) {
        int t2 = __shfl_up(sc, o, 64);
        sc += (lane >= o) ? t2 : 0;
    }
    int C = __shfl(sc, 63, 64);
    int base = sc - cnt;
    if (C > 128) C = 128;
    unsigned long long* pq = pool[qw];
#define WPOOL(I, VI) if (I < cnt) { int p = base + I; if (p < 128) pq[p] = VI; }
    WPOOL(0, V0) WPOOL(1, V1) WPOOL(2, V2) WPOOL(3, V3)
    WPOOL(4, V4) WPOOL(5, V5) WPOOL(6, V6) WPOOL(7, V7)
#undef WPOOL
    __syncthreads();

    // (4) rank by counting greater pool keys (broadcast LDS reads)
    bool h1 = lane < C;
    bool h2 = (lane + 64) < C;
    unsigned long long k1 = h1 ? pq[lane] : 0ull;
    unsigned long long k2 = h2 ? pq[lane + 64] : 0ull;
    int r1 = 0, r2 = 0;
    for (int i = 0; i < C; ++i) {
        unsigned long long ki = pq[i];
        r1 += (int)(ki > k1);
        r2 += (int)(ki > k2);
    }
    unsigned* kout = knn + (size_t)q*20;
    if (h1 && r1 < 20) kout[r1] = 16383u - (unsigned)(k1 & 0x3FFFull);
    if (h2 && r2 < 20) kout[r2] = 16383u - (unsigned)(k2 & 0x3FFFull);
}

// ---------------- kernel 5: GEMM for feature part of G and T2 ----------------
// G[n][64+o] = F_n . WA_f[o]   ;  T2[n][64+o] = F_n . WB_f[o] + CB_f[o]
__global__ __launch_bounds__(128) void kgemm(const float* __restrict__ feat,
                                             const float* __restrict__ wsf,
                                             float* __restrict__ G, float* __restrict__ T2)
{
    __shared__ float As[32][64];
    __shared__ float Bs[32][128];
    const float* WKC = wsf + OFF_WKC/4;
    const float* CBF = wsf + OFF_CBF/4;
    const int tid = threadIdx.x;
    const int n0 = blockIdx.x * 64;
    const int tx = tid & 15, ty = tid >> 4;
    float acc[8][8] = {};
    for (int kc = 0; kc < 4; ++kc) {
        int c0 = kc * 32;
        for (int i = tid; i < 2048; i += 128) {
            int cl = i >> 6, nl = i & 63;
            As[cl][nl] = feat[(size_t)(c0 + cl)*NPT + n0 + nl];
        }
        for (int i = tid; i < 4096; i += 128) {
            int cl = i >> 7, ol = i & 127;
            Bs[cl][ol] = WKC[(c0 + cl)*128 + ol];
        }
        __syncthreads();
        for (int cc = 0; cc < 32; ++cc) {
            float av[8], bv[8];
#pragma unroll
            for (int r = 0; r < 8; ++r) av[r] = As[cc][ty*8 + r];
#pragma unroll
            for (int s = 0; s < 8; ++s) bv[s] = Bs[cc][tx*8 + s];
#pragma unroll
            for (int r = 0; r < 8; ++r)
#pragma unroll
                for (int s = 0; s < 8; ++s)
                    acc[r][s] = fmaf(av[r], bv[s], acc[r][s]);
        }
        __syncthreads();
    }
#pragma unroll
    for (int r = 0; r < 8; ++r) {
        int n = n0 + ty*8 + r;
        if (tx < 8) {
            float* dst = G + (size_t)n*128 + 64 + tx*8;
#pragma unroll
            for (int s = 0; s < 8; ++s) dst[s] = acc[r][s];
        } else {
            int ob = (tx - 8)*8;
            float* dst = T2 + (size_t)n*128 + 64 + ob;
#pragma unroll
            for (int s = 0; s < 8; ++s) dst[s] = acc[r][s] + CBF[ob + s];
        }
    }
}

// ---------------- kernel 6: xyz part of G and T2 ----------------
__global__ __launch_bounds__(256) void kxpart(const float* __restrict__ xyz,
                                              const float* __restrict__ wsf,
                                              float* __restrict__ G, float* __restrict__ T2)
{
    const float4* WAX = (const float4*)(wsf + OFF_WAX/4);
    const float4* WBX = (const float4*)(wsf + OFF_WBX/4);
    const float*  CBX = wsf + OFF_CBX/4;
    const int tid = threadIdx.x;
    const int o = tid & 63;
    const int n = blockIdx.x*4 + (tid >> 6);
    float x = xyz[n], y = xyz[NPT+n], z = xyz[2*NPT+n];
    float4 A = WAX[o], B = WBX[o];
    G[(size_t)n*128 + o]  = fmaf(x, A.x, fmaf(y, A.y, z*A.z));
    T2[(size_t)n*128 + o] = fmaf(x, B.x, fmaf(y, B.y, fmaf(z, B.z, CBX[o])));
}

// ---------------- kernel 7: gather + max-pool + f1/f2 + partials ----------------
__global__ __launch_bounds__(256) void kgather(const float* __restrict__ wsf,
                                               const unsigned* __restrict__ knn,
                                               const float* __restrict__ G,
                                               const float* __restrict__ T2,
                                               const float* __restrict__ wd1,
                                               const float* __restrict__ wd2,
                                               float* __restrict__ F, float* __restrict__ F1,
                                               float* __restrict__ F2, float* __restrict__ SPm,
                                               float* __restrict__ PART)
{
    __shared__ float fsh[64][136];
    __shared__ float w1s[16][136];
    __shared__ float w2s[16][136];
    __shared__ float f1sh[64][16];
    __shared__ float f2p[64][4];
    const int tid = threadIdx.x;
    for (int i = tid; i < 2048; i += 256) {
        int o = i >> 7, cc = i & 127;
        w1s[o][cc] = wd1[i];
        w2s[o][cc] = wd2[i];
    }
    const int nl = tid >> 2, qt = tid & 3;
    const int n = blockIdx.x*64 + nl;
    const unsigned* ip = knn + (size_t)n*20;
    float acc[32];
#pragma unroll
    for (int e = 0; e < 32; ++e) acc[e] = NEG_INF;
    for (int k = 0; k < 20; ++k) {
        unsigned j = ip[k];
        const float4* g4 = (const float4*)(G + (size_t)j*128 + qt*32);
#pragma unroll
        for (int r = 0; r < 8; ++r) {
            float4 gv = g4[r];
            acc[r*4+0] = fmaxf(acc[r*4+0], gv.x);
            acc[r*4+1] = fmaxf(acc[r*4+1], gv.y);
            acc[r*4+2] = fmaxf(acc[r*4+2], gv.z);
            acc[r*4+3] = fmaxf(acc[r*4+3], gv.w);
        }
    }
    const float4* t4 = (const float4*)(T2 + (size_t)n*128 + qt*32);
    float4* fg = (float4*)(F + (size_t)n*128 + qt*32);
    float4* fs = (float4*)&fsh[nl][qt*32];
#pragma unroll
    for (int r = 0; r < 8; ++r) {
        float4 tv = t4[r];
        float4 o4;
        o4.x = fmaxf(acc[r*4+0] + tv.x, 0.f);
        o4.y = fmaxf(acc[r*4+1] + tv.y, 0.f);
        o4.z = fmaxf(acc[r*4+2] + tv.z, 0.f);
        o4.w = fmaxf(acc[r*4+3] + tv.w, 0.f);
        fg[r] = o4; fs[r] = o4;
    }
    __syncthreads();
    // phase 2: f1/f2 (4 outputs each per thread)
    float a1[4] = {0,0,0,0}, a2[4] = {0,0,0,0};
    const int ob = qt*4;
    for (int c4 = 0; c4 < 32; ++c4) {
        float4 fv = ((const float4*)&fsh[nl][0])[c4];
#pragma unroll
        for (int r = 0; r < 4; ++r) {
            float4 wv1 = ((const float4*)&w1s[ob + r][0])[c4];
            float4 wv2 = ((const float4*)&w2s[ob + r][0])[c4];
            a1[r] = fmaf(fv.x, wv1.x, fmaf(fv.y, wv1.y, fmaf(fv.z, wv1.z, fmaf(fv.w, wv1.w, a1[r]))));
            a2[r] = fmaf(fv.x, wv2.x, fmaf(fv.y, wv2.y, fmaf(fv.z, wv2.z, fmaf(fv.w, wv2.w, a2[r]))));
        }
    }
    float s2sum = 0.f;
#pragma unroll
    for (int r = 0; r < 4; ++r) {
        a1[r] = fmaxf(a1[r], 0.f);
        a2[r] = fmaxf(a2[r], 0.f);
        s2sum += a2[r];
        F1[(size_t)n*16 + ob + r] = a1[r];
        F2[(size_t)n*16 + ob + r] = a2[r];
        f1sh[nl][ob + r] = a1[r];
    }
    f2p[nl][qt] = s2sum;
    __syncthreads();
    if (qt == 0)
        SPm[n] = (f2p[nl][0] + f2p[nl][1] + f2p[nl][2] + f2p[nl][3]) * (1.0f/16.0f);
    if (tid < 16) {
        float s = 0.f;
        for (int r = 0; r < 64; ++r) s += f1sh[r][tid];
        PART[blockIdx.x*16 + tid] = s;
    }
}

// ---------------- kernel 8: reduce channel mean ----------------
__global__ __launch_bounds__(64) void kch(const float* __restrict__ PART, float* __restrict__ CH)
{
    const int tid = threadIdx.x;
    if (tid < 16) {
        float s = 0.f;
        for (int b = 0; b < 256; ++b) s += PART[b*16 + tid];
        CH[tid] = s * (1.0f/16384.0f);
    }
}

// ---------------- kernel 9: final head + mish + transpose ----------------
__global__ __launch_bounds__(64) void kfinal(const float* __restrict__ wsf,
                                             const float* __restrict__ F,
                                             const float* __restrict__ F1,
                                             const float* __restrict__ F2,
                                             const float* __restrict__ SPm,
                                             const float* __restrict__ CH,
                                             float* __restrict__ out)
{
    const float* WUP = wsf + OFF_WUP/4;
    const float* BUP = wsf + OFF_BUP/4;
    const int n = blockIdx.x*64 + threadIdx.x;
    float spv = SPm[n];
    float fin[16];
    const float4* f14 = (const float4*)(F1 + (size_t)n*16);
    const float4* f24 = (const float4*)(F2 + (size_t)n*16);
#pragma unroll
    for (int c4 = 0; c4 < 4; ++c4) {
        float4 a = f14[c4], b = f24[c4];
        fin[c4*4+0] = sqrtf(fmaf(CH[c4*4+0], spv, 1e-12f)) + a.x + b.x;
        fin[c4*4+1] = sqrtf(fmaf(CH[c4*4+1], spv, 1e-12f)) + a.y + b.y;
        fin[c4*4+2] = sqrtf(fmaf(CH[c4*4+2], spv, 1e-12f)) + a.z + b.z;
        fin[c4*4+3] = sqrtf(fmaf(CH[c4*4+3], spv, 1e-12f)) + a.w + b.w;
    }
    const float4* fF = (const float4*)(F + (size_t)n*128);
    for (int o4 = 0; o4 < 32; ++o4) {
        float4 fv = fF[o4];
        float fa[4] = {fv.x, fv.y, fv.z, fv.w};
#pragma unroll
        for (int e = 0; e < 4; ++e) {
            int o = o4*4 + e;
            float u = BUP[o];
#pragma unroll
            for (int c = 0; c < 16; ++c) u = fmaf(fin[c], WUP[o*16 + c], u);
            u = fmaxf(u, 0.f);
            float fl = fa[e] - u;
            // mish: fl * tanh(softplus(fl)) ; tanh(log1p(e^x)) = ((1+e^x)^2-1)/((1+e^x)^2+1)
            float flc = fminf(fl, 15.f);
            float t = expf(flc);
            float w = 1.f + t;
            float w2 = w*w;
            float th = (w2 - 1.f) / (w2 + 1.f);
            float res = (fl > 15.f) ? fl : fl * th;
            out[(size_t)o*NPT + n] = res;
        }
    }
}

extern "C" void kernel_launch(void* const* d_in, const int* in_sizes, int n_in,
                              void* d_out, int out_size, void* d_ws, size_t ws_size,
                              hipStream_t stream) {
    const float* xyz  = (const float*)d_in[0];
    const float* feat = (const float*)d_in[1];
    const float* w1   = (const float*)d_in[2];
    const float* b1   = (const float*)d_in[3];
    const float* g1   = (const float*)d_in[4];
    const float* bb1  = (const float*)d_in[5];
    const float* m1   = (const float*)d_in[6];
    const float* v1   = (const float*)d_in[7];
    const float* w2   = (const float*)d_in[8];
    const float* b2   = (const float*)d_in[9];
    const float* g2   = (const float*)d_in[10];
    const float* bb2  = (const float*)d_in[11];
    const float* m2   = (const float*)d_in[12];
    const float* v2   = (const float*)d_in[13];
    const float* wd1  = (const float*)d_in[14];
    const float* wd2  = (const float*)d_in[15];
    const float* wup  = (const float*)d_in[16];
    const float* bup  = (const float*)d_in[17];
    const float* gu   = (const float*)d_in[18];
    const float* bu2  = (const float*)d_in[19];
    const float* mu   = (const float*)d_in[20];
    const float* vu   = (const float*)d_in[21];
    float* out = (float*)d_out;

    float* wsf = (float*)d_ws;
    unsigned* bm   = (unsigned*)((char*)d_ws + OFF_R);
    unsigned* knn  = (unsigned*)((char*)d_ws + OFF_KNN);
    float* TAU  = (float*)((char*)d_ws + OFF_TAU);
    float* PART = (float*)((char*)d_ws + OFF_PART);
    float* CH   = (float*)((char*)d_ws + OFF_CH);
    // region R reused after ksel
    float* G  = (float*)((char*)d_ws + OFF_R);
    float* T2 = G  + 2097152;
    float* F  = T2 + 2097152;
    float* F1 = F  + 2097152;
    float* F2 = F1 + 262144;
    float* SPm = F2 + 262144;

    kprep<<<dim3(65),  dim3(256), 0, stream>>>(xyz, w1,b1,g1,bb1,m1,v1,
                                               w2,b2,g2,bb2,m2,v2,
                                               wup,bup,gu,bu2,mu,vu, wsf);
    ktau <<<dim3(512), dim3(256), 0, stream>>>(wsf, TAU);
    kpush<<<dim3(1024), dim3(256), 0, stream>>>(wsf, TAU, bm);
    ksel <<<dim3(4096), dim3(256), 0, stream>>>(wsf, bm, knn);
    kgemm<<<dim3(256), dim3(128), 0, stream>>>(feat, wsf, G, T2);
    kxpart<<<dim3(4096), dim3(256), 0, stream>>>(xyz, wsf, G, T2);
    kgather<<<dim3(256), dim3(256), 0, stream>>>(wsf, knn, G, T2, wd1, wd2, F, F1, F2, SPm, PART);
    kch  <<<dim3(1),   dim3(64), 0, stream>>>(PART, CH);
    kfinal<<<dim3(256), dim3(64), 0, stream>>>(wsf, F, F1, F2, SPm, CH, out);
}

// Round 12
// 260.467 us; speedup vs baseline: 1.2197x; 1.0103x over previous
//
#include <hip/hip_runtime.h>

#define NPT 16384
#define NEG_INF (-3.402823466e38f)

// ---- workspace byte offsets ----
#define OFF_PTS4  0u            // 16384 * 16          = 262144
#define OFF_WKC   262144u       // 128*128*4           = 65536
#define OFF_WAX   327680u       // 64*4*4              = 1024
#define OFF_WBX   328704u       // 1024
#define OFF_CBX   329728u       // 256
#define OFF_CBF   329984u       // 256
#define OFF_WUP   330240u       // 128*16*4            = 8192
#define OFF_BUP   338432u       // 512
#define OFF_TAU   338944u       // 16384*4             = 65536
#define OFF_KNN   666624u       // 16384*20*4          = 1310720
#define OFF_PART  1977344u      // 256*16*4            = 16384
#define OFF_CH    1993728u      // 256
#define OFF_R     1994240u      // reused: survivor bitmap u32[16384][512] = 33554432
                                // after ksel: G(8MB), T2(8MB), F(8MB), F1(1MB), F2(1MB), SP(64KB)

__device__ __forceinline__ float pd_score(float qx2, float qy2, float qz2, float4 c) {
    // fast screening score = 2*dot(q,c) - |c|^2 (query-constant -|q|^2 dropped; same ranking)
    return fmaf(qx2, c.x, fmaf(qy2, c.y, fmaf(qz2, c.z, -c.w)));
}

__device__ __forceinline__ unsigned sortable_f(float v) {
    unsigned b = __float_as_uint(v);
    return (b & 0x80000000u) ? ~b : (b | 0x80000000u);
}

// ---------------- kernel 1: weight folds + pts4 ----------------
__global__ __launch_bounds__(256) void kprep(
    const float* __restrict__ xyz,
    const float* __restrict__ w1, const float* __restrict__ b1,
    const float* __restrict__ g1, const float* __restrict__ bb1,
    const float* __restrict__ m1, const float* __restrict__ v1,
    const float* __restrict__ w2, const float* __restrict__ b2,
    const float* __restrict__ g2, const float* __restrict__ bb2,
    const float* __restrict__ m2, const float* __restrict__ v2,
    const float* __restrict__ wup, const float* __restrict__ bup,
    const float* __restrict__ gu, const float* __restrict__ bu2,
    const float* __restrict__ mu, const float* __restrict__ vu,
    float* __restrict__ wsf)
{
    const int tid = threadIdx.x;
    if (blockIdx.x == 0) {
        float* WKC = wsf + OFF_WKC/4;
        float* WAX = wsf + OFF_WAX/4;
        float* WBX = wsf + OFF_WBX/4;
        float* CBX = wsf + OFF_CBX/4;
        float* CBF = wsf + OFF_CBF/4;
        float* WUP = wsf + OFF_WUP/4;
        float* BUP = wsf + OFF_BUP/4;
        for (int i = tid; i < 16384; i += 256) {
            int c = i >> 7, o = i & 127, oo = o & 63;
            float s2 = g2[oo] * rsqrtf(v2[oo] + 1e-5f);
            float val = (o < 64) ? s2 * w2[oo*256 + c]
                                 : s2 * (w2[oo*256 + 128 + c] - w2[oo*256 + c]);
            WKC[c*128 + o] = val;
        }
        if (tid < 64) {
            int o = tid;
            float s1 = g1[o] * rsqrtf(v1[o] + 1e-5f);
            WAX[o*4+0] = s1 * w1[o*6+0];
            WAX[o*4+1] = s1 * w1[o*6+1];
            WAX[o*4+2] = s1 * w1[o*6+2];
            WAX[o*4+3] = 0.f;
            WBX[o*4+0] = s1 * (w1[o*6+3] - w1[o*6+0]);
            WBX[o*4+1] = s1 * (w1[o*6+4] - w1[o*6+1]);
            WBX[o*4+2] = s1 * (w1[o*6+5] - w1[o*6+2]);
            WBX[o*4+3] = 0.f;
            CBX[o] = s1 * b1[o] + (bb1[o] - m1[o]*s1);
            float s2b = g2[o] * rsqrtf(v2[o] + 1e-5f);
            CBF[o] = s2b * b2[o] + (bb2[o] - m2[o]*s2b);
        }
        if (tid < 128) {
            int o = tid;
            float su = gu[o] * rsqrtf(vu[o] + 1e-5f);
            for (int c = 0; c < 16; ++c) WUP[o*16+c] = su * wup[o*16+c];
            BUP[o] = su * bup[o] + (bu2[o] - mu[o]*su);
        }
    } else {
        // np-f32-exact |p|^2: ((x*x + y*y) + z*z), no FMA contraction, matching
        // np.sum(xyz*xyz, axis=1) sequential f32 reduction.
        #pragma clang fp contract(off)
        int n = (blockIdx.x - 1)*256 + tid;
        float x = xyz[n], y = xyz[NPT+n], z = xyz[2*NPT+n];
        float4 p; p.x = x; p.y = y; p.z = z;
        p.w = (x*x + y*y) + z*z;
        ((float4*)(wsf + OFF_PTS4/4))[n] = p;
    }
}

// ---------------- kernel 2: per-query threshold tau ----------------
// tau[q] = (20th-largest of union(8 per-thread top-6) over candidates [0,1024)) - margin.
// union-20th <= subset-20th <= full-20th, and the 5e-4 margin covers all screening-score
// vs np-f32-pd discrepancies (<= ~3e-5) -> bitmap survivors are a superset of np's top-20.
__global__ __launch_bounds__(256) void ktau(const float* __restrict__ wsf, float* __restrict__ tau)
{
    const float4* pts4 = (const float4*)(wsf + OFF_PTS4/4);
    __shared__ float4 sp[1024];
    __shared__ float t6[32][8][6];
    const int tid = threadIdx.x;
    for (int i = tid; i < 1024; i += 256) sp[i] = pts4[i];
    __syncthreads();
    const int ql = tid >> 3, t = tid & 7;
    const int q = blockIdx.x*32 + ql;
    float4 qp = pts4[q];
    float qx2 = qp.x + qp.x, qy2 = qp.y + qp.y, qz2 = qp.z + qp.z;
    float v0 = NEG_INF, v1 = NEG_INF, v2 = NEG_INF, v3 = NEG_INF, v4 = NEG_INF, v5 = NEG_INF;
    const int jb = t*128;
    for (int i = 0; i < 128; ++i) {
        float v = pd_score(qx2, qy2, qz2, sp[jb + i]);
        float n5 = v > v5 ? (v > v4 ? v4 : v) : v5;
        float n4 = v > v4 ? (v > v3 ? v3 : v) : v4;
        float n3 = v > v3 ? (v > v2 ? v2 : v) : v3;
        float n2 = v > v2 ? (v > v1 ? v1 : v) : v2;
        float n1 = v > v1 ? (v > v0 ? v0 : v) : v1;
        float n0 = v > v0 ? v : v0;
        v0 = n0; v1 = n1; v2 = n2; v3 = n3; v4 = n4; v5 = n5;
    }
    t6[ql][t][0] = v0; t6[ql][t][1] = v1; t6[ql][t][2] = v2;
    t6[ql][t][3] = v3; t6[ql][t][4] = v4; t6[ql][t][5] = v5;
    __syncthreads();
    if (t == 0) {
        int p0=0,p1=0,p2=0,p3=0,p4=0,p5=0,p6=0,p7=0;
        float last = NEG_INF;
        for (int it = 0; it < 20; ++it) {
            float best = NEG_INF; int bl = -1;
#define CHK(L, PL) { float h = t6[ql][L][(PL) < 6 ? (PL) : 5]; if (((PL) < 6) && (h > best)) { best = h; bl = L; } }
            CHK(0,p0) CHK(1,p1) CHK(2,p2) CHK(3,p3) CHK(4,p4) CHK(5,p5) CHK(6,p6) CHK(7,p7)
#undef CHK
            p0 += (bl==0); p1 += (bl==1); p2 += (bl==2); p3 += (bl==3);
            p4 += (bl==4); p5 += (bl==5); p6 += (bl==6); p7 += (bl==7);
            last = best;
        }
        tau[q] = last - 5e-4f;   // conservative margin (covers fmaf-chain vs np-f32 rounding)
    }
}

// ---------------- kernel 3: streaming scan -> survivor BITMAP ----------------
// Round-11 post-mortem: writes fixed (exactly 32MB) but dur only 66->62us: the limiter
// is s_load latency at 33% occupancy (36KB LDS caps 4 blocks/CU; grid 1024 = exactly
// 4/CU, zero headroom). This round: chunks 1024->512 cands (grid 2048 = 8 blocks/CU),
// staging 4 uint4/thread in LDS [256][5] (20KB -> 8 blocks/CU fits 160KB exactly,
// VGPR<=64 keeps 8 waves/SIMD) -> up to 32 waves/CU. Writeout = one fully-dirty 64B
// sector back-to-back (round-10 data showed 64B write-back granule -> no amplification).
// Also folds -tau into the first fma (6 VALU/cand): s' = fma chain starting at -t0,
// compare s' >= |c|^2 (scalar src0). Same superset guarantee (5e-4 margin >> assoc delta).
__global__ __launch_bounds__(256) void kpush(const float* __restrict__ wsf,
                                             const float* __restrict__ tau,
                                             unsigned* __restrict__ bm)
{
    const float4* pts4 = (const float4*)(wsf + OFF_PTS4/4);
    __shared__ uint4 st[256][5];   // 20KB; slot [tid][g], pad 5 -> stride 20 words, 2-way banks
    const int qg = blockIdx.x >> 5, c = blockIdx.x & 31;
    const int tid = threadIdx.x;
    const int jbase = c * 512;
    const int q = qg*256 + tid;
    float4 a = pts4[q];
    float ax2 = a.x + a.x, ay2 = a.y + a.y, az2 = a.z + a.z;
    float nt0 = -tau[q];
    for (int g = 0; g < 4; ++g) {
        unsigned wd[4];
#pragma unroll
        for (int u = 0; u < 4; ++u) {
            const int base = jbase + (g*4 + u)*32;
            unsigned w = 0u;
#pragma unroll
            for (int k = 0; k < 32; k += 4) {
                float4 d0 = pts4[base + k];
                float4 d1 = pts4[base + k + 1];
                float4 d2 = pts4[base + k + 2];
                float4 d3 = pts4[base + k + 3];
                float s0 = fmaf(az2, d0.z, fmaf(ay2, d0.y, fmaf(ax2, d0.x, nt0)));
                float s1 = fmaf(az2, d1.z, fmaf(ay2, d1.y, fmaf(ax2, d1.x, nt0)));
                float s2 = fmaf(az2, d2.z, fmaf(ay2, d2.y, fmaf(ax2, d2.x, nt0)));
                float s3 = fmaf(az2, d3.z, fmaf(ay2, d3.y, fmaf(ax2, d3.x, nt0)));
                w |= (s0 >= d0.w) ? (1u << k)       : 0u;
                w |= (s1 >= d1.w) ? (1u << (k + 1)) : 0u;
                w |= (s2 >= d2.w) ? (1u << (k + 2)) : 0u;
                w |= (s3 >= d3.w) ? (1u << (k + 3)) : 0u;
            }
            wd[u] = w;
        }
        uint4 o; o.x = wd[0]; o.y = wd[1]; o.z = wd[2]; o.w = wd[3];
        st[tid][g] = o;
    }
    // back-to-back 64B-sector writeout (thread-private slot: no barrier needed)
    uint4* dst = (uint4*)(bm + (size_t)q*512 + c*16);
#pragma unroll
    for (int g = 0; g < 4; ++g) dst[g] = st[tid][g];
}

// ---------------- kernel 4: exact top-20 from bitmap — pool-and-rank ----------------
//  (1) per-lane depth-8 sorted register list from the lane's 256-candidate bitmap
//      window (np-f32 bit-exact scores, fp contract off);
//  (2) ONE bitonic sort (21 shfl stages) of the 64 lane-maxima -> theta = 20th-largest
//      lane-max (ascending sort, lane 44). theta <= 20th-largest key overall;
//  (3) prefix-sum compaction of all kept keys >= theta into an LDS pool (E[C]~24);
//  (4) each pool key's exact global rank = #greater pool keys (C broadcast LDS reads);
//      rank<20 -> knn[q*20+rank]: exact np descending top_k order incl. tie-breaks.
// Coverage: lane needs >8 of the top-20 in its window to drop one (P ~ 6e-11 * 16384).
#define KS(A,B) V##A = (kk > V##B) ? V##B : ((kk > V##A) ? kk : V##A);
__global__ __launch_bounds__(256) void ksel(const float* __restrict__ wsf,
                                            const unsigned* __restrict__ bm,
                                            unsigned* __restrict__ knn)
{
    #pragma clang fp contract(off)
    const float4* pts4 = (const float4*)(wsf + OFF_PTS4/4);
    __shared__ unsigned long long pool[4][128];
    const int lane = threadIdx.x & 63;
    const int qw   = threadIdx.x >> 6;
    const int q = blockIdx.x*4 + qw;
    float4 qp = pts4[q];

    unsigned long long V0=0,V1=0,V2=0,V3=0,V4=0,V5=0,V6=0,V7=0;

    const uint4* row = (const uint4*)(bm + (size_t)q*512) + lane*2;
    uint4 a0 = row[0], a1 = row[1];
    unsigned wv[8] = {a0.x, a0.y, a0.z, a0.w, a1.x, a1.y, a1.z, a1.w};
#pragma unroll
    for (int t = 0; t < 8; ++t) {
        unsigned w = wv[t];
        const int wbase = (lane*8 + t)*32;
        while (w) {
            int b = __ffs(w) - 1; w &= w - 1;
            int j = wbase + b;
            float4 cp = pts4[j];
            float d  = (qp.x*cp.x + qp.y*cp.y) + qp.z*cp.z;
            float pd = (2.0f*d - qp.w) - cp.w;
            unsigned long long kk = ((unsigned long long)sortable_f(pd) << 14)
                                  | (unsigned long long)(16383 - j);
            if (kk > V7) {
                KS(7,6) KS(6,5) KS(5,4) KS(4,3) KS(3,2) KS(2,1) KS(1,0)
                V0 = (kk > V0) ? kk : V0;
            }
        }
    }

    // (2) bitonic ascending sort of lane maxima; theta at lane 44 (20th largest)
    unsigned long long s = V0;
#pragma unroll
    for (int k = 2; k <= 64; k <<= 1) {
#pragma unroll
        for (int j = k >> 1; j > 0; j >>= 1) {
            unsigned long long o = __shfl_xor(s, j, 64);
            bool up = ((lane & k) == 0);
            bool lower = ((lane & j) == 0);
            s = (lower == up) ? ((s < o) ? s : o) : ((s > o) ? s : o);
        }
    }
    unsigned long long theta = __shfl(s, 44, 64);

    // (3) compact kept keys >= theta into LDS pool
    int cnt = (int)(V0 >= theta) + (int)(V1 >= theta) + (int)(V2 >= theta)
            + (int)(V3 >= theta) + (int)(V4 >= theta) + (int)(V5 >= theta)
            + (int)(V6 >= theta) + (int)(V7 >= theta);
    int sc = cnt;
#pragma unroll
    for (int o = 1; o < 64; o <<= 1) {
        int t2 = __shfl_up(sc, o, 64);
        sc += (lane >= o) ? t2 : 0;
    }
    int C = __shfl(sc, 63, 64);
    int base = sc - cnt;
    if (C > 128) C = 128;
    unsigned long long* pq = pool[qw];
#define WPOOL(I, VI) if (I < cnt) { int p = base + I; if (p < 128) pq[p] = VI; }
    WPOOL(0, V0) WPOOL(1, V1) WPOOL(2, V2) WPOOL(3, V3)
    WPOOL(4, V4) WPOOL(5, V5) WPOOL(6, V6) WPOOL(7, V7)
#undef WPOOL
    __syncthreads();

    // (4) rank by counting greater pool keys (broadcast LDS reads)
    bool h1 = lane < C;
    bool h2 = (lane + 64) < C;
    unsigned long long k1 = h1 ? pq[lane] : 0ull;
    unsigned long long k2 = h2 ? pq[lane + 64] : 0ull;
    int r1 = 0, r2 = 0;
    for (int i = 0; i < C; ++i) {
        unsigned long long ki = pq[i];
        r1 += (int)(ki > k1);
        r2 += (int)(ki > k2);
    }
    unsigned* kout = knn + (size_t)q*20;
    if (h1 && r1 < 20) kout[r1] = 16383u - (unsigned)(k1 & 0x3FFFull);
    if (h2 && r2 < 20) kout[r2] = 16383u - (unsigned)(k2 & 0x3FFFull);
}

// ---------------- kernel 5: GEMM for feature part of G and T2 ----------------
// G[n][64+o] = F_n . WA_f[o]   ;  T2[n][64+o] = F_n . WB_f[o] + CB_f[o]
__global__ __launch_bounds__(128) void kgemm(const float* __restrict__ feat,
                                             const float* __restrict__ wsf,
                                             float* __restrict__ G, float* __restrict__ T2)
{
    __shared__ float As[32][64];
    __shared__ float Bs[32][128];
    const float* WKC = wsf + OFF_WKC/4;
    const float* CBF = wsf + OFF_CBF/4;
    const int tid = threadIdx.x;
    const int n0 = blockIdx.x * 64;
    const int tx = tid & 15, ty = tid >> 4;
    float acc[8][8] = {};
    for (int kc = 0; kc < 4; ++kc) {
        int c0 = kc * 32;
        for (int i = tid; i < 2048; i += 128) {
            int cl = i >> 6, nl = i & 63;
            As[cl][nl] = feat[(size_t)(c0 + cl)*NPT + n0 + nl];
        }
        for (int i = tid; i < 4096; i += 128) {
            int cl = i >> 7, ol = i & 127;
            Bs[cl][ol] = WKC[(c0 + cl)*128 + ol];
        }
        __syncthreads();
        for (int cc = 0; cc < 32; ++cc) {
            float av[8], bv[8];
#pragma unroll
            for (int r = 0; r < 8; ++r) av[r] = As[cc][ty*8 + r];
#pragma unroll
            for (int s = 0; s < 8; ++s) bv[s] = Bs[cc][tx*8 + s];
#pragma unroll
            for (int r = 0; r < 8; ++r)
#pragma unroll
                for (int s = 0; s < 8; ++s)
                    acc[r][s] = fmaf(av[r], bv[s], acc[r][s]);
        }
        __syncthreads();
    }
#pragma unroll
    for (int r = 0; r < 8; ++r) {
        int n = n0 + ty*8 + r;
        if (tx < 8) {
            float* dst = G + (size_t)n*128 + 64 + tx*8;
#pragma unroll
            for (int s = 0; s < 8; ++s) dst[s] = acc[r][s];
        } else {
            int ob = (tx - 8)*8;
            float* dst = T2 + (size_t)n*128 + 64 + ob;
#pragma unroll
            for (int s = 0; s < 8; ++s) dst[s] = acc[r][s] + CBF[ob + s];
        }
    }
}

// ---------------- kernel 6: xyz part of G and T2 ----------------
__global__ __launch_bounds__(256) void kxpart(const float* __restrict__ xyz,
                                              const float* __restrict__ wsf,
                                              float* __restrict__ G, float* __restrict__ T2)
{
    const float4* WAX = (const float4*)(wsf + OFF_WAX/4);
    const float4* WBX = (const float4*)(wsf + OFF_WBX/4);
    const float*  CBX = wsf + OFF_CBX/4;
    const int tid = threadIdx.x;
    const int o = tid & 63;
    const int n = blockIdx.x*4 + (tid >> 6);
    float x = xyz[n], y = xyz[NPT+n], z = xyz[2*NPT+n];
    float4 A = WAX[o], B = WBX[o];
    G[(size_t)n*128 + o]  = fmaf(x, A.x, fmaf(y, A.y, z*A.z));
    T2[(size_t)n*128 + o] = fmaf(x, B.x, fmaf(y, B.y, fmaf(z, B.z, CBX[o])));
}

// ---------------- kernel 7: gather + max-pool + f1/f2 + partials ----------------
__global__ __launch_bounds__(256) void kgather(const float* __restrict__ wsf,
                                               const unsigned* __restrict__ knn,
                                               const float* __restrict__ G,
                                               const float* __restrict__ T2,
                                               const float* __restrict__ wd1,
                                               const float* __restrict__ wd2,
                                               float* __restrict__ F, float* __restrict__ F1,
                                               float* __restrict__ F2, float* __restrict__ SPm,
                                               float* __restrict__ PART)
{
    __shared__ float fsh[64][136];
    __shared__ float w1s[16][136];
    __shared__ float w2s[16][136];
    __shared__ float f1sh[64][16];
    __shared__ float f2p[64][4];
    const int tid = threadIdx.x;
    for (int i = tid; i < 2048; i += 256) {
        int o = i >> 7, cc = i & 127;
        w1s[o][cc] = wd1[i];
        w2s[o][cc] = wd2[i];
    }
    const int nl = tid >> 2, qt = tid & 3;
    const int n = blockIdx.x*64 + nl;
    const unsigned* ip = knn + (size_t)n*20;
    float acc[32];
#pragma unroll
    for (int e = 0; e < 32; ++e) acc[e] = NEG_INF;
    for (int k = 0; k < 20; ++k) {
        unsigned j = ip[k];
        const float4* g4 = (const float4*)(G + (size_t)j*128 + qt*32);
#pragma unroll
        for (int r = 0; r < 8; ++r) {
            float4 gv = g4[r];
            acc[r*4+0] = fmaxf(acc[r*4+0], gv.x);
            acc[r*4+1] = fmaxf(acc[r*4+1], gv.y);
            acc[r*4+2] = fmaxf(acc[r*4+2], gv.z);
            acc[r*4+3] = fmaxf(acc[r*4+3], gv.w);
        }
    }
    const float4* t4 = (const float4*)(T2 + (size_t)n*128 + qt*32);
    float4* fg = (float4*)(F + (size_t)n*128 + qt*32);
    float4* fs = (float4*)&fsh[nl][qt*32];
#pragma unroll
    for (int r = 0; r < 8; ++r) {
        float4 tv = t4[r];
        float4 o4;
        o4.x = fmaxf(acc[r*4+0] + tv.x, 0.f);
        o4.y = fmaxf(acc[r*4+1] + tv.y, 0.f);
        o4.z = fmaxf(acc[r*4+2] + tv.z, 0.f);
        o4.w = fmaxf(acc[r*4+3] + tv.w, 0.f);
        fg[r] = o4; fs[r] = o4;
    }
    __syncthreads();
    // phase 2: f1/f2 (4 outputs each per thread)
    float a1[4] = {0,0,0,0}, a2[4] = {0,0,0,0};
    const int ob = qt*4;
    for (int c4 = 0; c4 < 32; ++c4) {
        float4 fv = ((const float4*)&fsh[nl][0])[c4];
#pragma unroll
        for (int r = 0; r < 4; ++r) {
            float4 wv1 = ((const float4*)&w1s[ob + r][0])[c4];
            float4 wv2 = ((const float4*)&w2s[ob + r][0])[c4];
            a1[r] = fmaf(fv.x, wv1.x, fmaf(fv.y, wv1.y, fmaf(fv.z, wv1.z, fmaf(fv.w, wv1.w, a1[r]))));
            a2[r] = fmaf(fv.x, wv2.x, fmaf(fv.y, wv2.y, fmaf(fv.z, wv2.z, fmaf(fv.w, wv2.w, a2[r]))));
        }
    }
    float s2sum = 0.f;
#pragma unroll
    for (int r = 0; r < 4; ++r) {
        a1[r] = fmaxf(a1[r], 0.f);
        a2[r] = fmaxf(a2[r], 0.f);
        s2sum += a2[r];
        F1[(size_t)n*16 + ob + r] = a1[r];
        F2[(size_t)n*16 + ob + r] = a2[r];
        f1sh[nl][ob + r] = a1[r];
    }
    f2p[nl][qt] = s2sum;
    __syncthreads();
    if (qt == 0)
        SPm[n] = (f2p[nl][0] + f2p[nl][1] + f2p[nl][2] + f2p[nl][3]) * (1.0f/16.0f);
    if (tid < 16) {
        float s = 0.f;
        for (int r = 0; r < 64; ++r) s += f1sh[r][tid];
        PART[blockIdx.x*16 + tid] = s;
    }
}

// ---------------- kernel 8: reduce channel mean ----------------
__global__ __launch_bounds__(64) void kch(const float* __restrict__ PART, float* __restrict__ CH)
{
    const int tid = threadIdx.x;
    if (tid < 16) {
        float s = 0.f;
        for (int b = 0; b < 256; ++b) s += PART[b*16 + tid];
        CH[tid] = s * (1.0f/16384.0f);
    }
}

// ---------------- kernel 9: final head + mish + transpose ----------------
__global__ __launch_bounds__(64) void kfinal(const float* __restrict__ wsf,
                                             const float* __restrict__ F,
                                             const float* __restrict__ F1,
                                             const float* __restrict__ F2,
                                             const float* __restrict__ SPm,
                                             const float* __restrict__ CH,
                                             float* __restrict__ out)
{
    const float* WUP = wsf + OFF_WUP/4;
    const float* BUP = wsf + OFF_BUP/4;
    const int n = blockIdx.x*64 + threadIdx.x;
    float spv = SPm[n];
    float fin[16];
    const float4* f14 = (const float4*)(F1 + (size_t)n*16);
    const float4* f24 = (const float4*)(F2 + (size_t)n*16);
#pragma unroll
    for (int c4 = 0; c4 < 4; ++c4) {
        float4 a = f14[c4], b = f24[c4];
        fin[c4*4+0] = sqrtf(fmaf(CH[c4*4+0], spv, 1e-12f)) + a.x + b.x;
        fin[c4*4+1] = sqrtf(fmaf(CH[c4*4+1], spv, 1e-12f)) + a.y + b.y;
        fin[c4*4+2] = sqrtf(fmaf(CH[c4*4+2], spv, 1e-12f)) + a.z + b.z;
        fin[c4*4+3] = sqrtf(fmaf(CH[c4*4+3], spv, 1e-12f)) + a.w + b.w;
    }
    const float4* fF = (const float4*)(F + (size_t)n*128);
    for (int o4 = 0; o4 < 32; ++o4) {
        float4 fv = fF[o4];
        float fa[4] = {fv.x, fv.y, fv.z, fv.w};
#pragma unroll
        for (int e = 0; e < 4; ++e) {
            int o = o4*4 + e;
            float u = BUP[o];
#pragma unroll
            for (int c = 0; c < 16; ++c) u = fmaf(fin[c], WUP[o*16 + c], u);
            u = fmaxf(u, 0.f);
            float fl = fa[e] - u;
            // mish: fl * tanh(softplus(fl)) ; tanh(log1p(e^x)) = ((1+e^x)^2-1)/((1+e^x)^2+1)
            float flc = fminf(fl, 15.f);
            float t = expf(flc);
            float w = 1.f + t;
            float w2 = w*w;
            float th = (w2 - 1.f) / (w2 + 1.f);
            float res = (fl > 15.f) ? fl : fl * th;
            out[(size_t)o*NPT + n] = res;
        }
    }
}

extern "C" void kernel_launch(void* const* d_in, const int* in_sizes, int n_in,
                              void* d_out, int out_size, void* d_ws, size_t ws_size,
                              hipStream_t stream) {
    const float* xyz  = (const float*)d_in[0];
    const float* feat = (const float*)d_in[1];
    const float* w1   = (const float*)d_in[2];
    const float* b1   = (const float*)d_in[3];
    const float* g1   = (const float*)d_in[4];
    const float* bb1  = (const float*)d_in[5];
    const float* m1   = (const float*)d_in[6];
    const float* v1   = (const float*)d_in[7];
    const float* w2   = (const float*)d_in[8];
    const float* b2   = (const float*)d_in[9];
    const float* g2   = (const float*)d_in[10];
    const float* bb2  = (const float*)d_in[11];
    const float* m2   = (const float*)d_in[12];
    const float* v2   = (const float*)d_in[13];
    const float* wd1  = (const float*)d_in[14];
    const float* wd2  = (const float*)d_in[15];
    const float* wup  = (const float*)d_in[16];
    const float* bup  = (const float*)d_in[17];
    const float* gu   = (const float*)d_in[18];
    const float* bu2  = (const float*)d_in[19];
    const float* mu   = (const float*)d_in[20];
    const float* vu   = (const float*)d_in[21];
    float* out = (float*)d_out;

    float* wsf = (float*)d_ws;
    unsigned* bm   = (unsigned*)((char*)d_ws + OFF_R);
    unsigned* knn  = (unsigned*)((char*)d_ws + OFF_KNN);
    float* TAU  = (float*)((char*)d_ws + OFF_TAU);
    float* PART = (float*)((char*)d_ws + OFF_PART);
    float* CH   = (float*)((char*)d_ws + OFF_CH);
    // region R reused after ksel
    float* G  = (float*)((char*)d_ws + OFF_R);
    float* T2 = G  + 2097152;
    float* F  = T2 + 2097152;
    float* F1 = F  + 2097152;
    float* F2 = F1 + 262144;
    float* SPm = F2 + 262144;

    kprep<<<dim3(65),  dim3(256), 0, stream>>>(xyz, w1,b1,g1,bb1,m1,v1,
                                               w2,b2,g2,bb2,m2,v2,
                                               wup,bup,gu,bu2,mu,vu, wsf);
    ktau <<<dim3(512), dim3(256), 0, stream>>>(wsf, TAU);
    kpush<<<dim3(2048), dim3(256), 0, stream>>>(wsf, TAU, bm);
    ksel <<<dim3(4096), dim3(256), 0, stream>>>(wsf, bm, knn);
    kgemm<<<dim3(256), dim3(128), 0, stream>>>(feat, wsf, G, T2);
    kxpart<<<dim3(4096), dim3(256), 0, stream>>>(xyz, wsf, G, T2);
    kgather<<<dim3(256), dim3(256), 0, stream>>>(wsf, knn, G, T2, wd1, wd2, F, F1, F2, SPm, PART);
    kch  <<<dim3(1),   dim3(64), 0, stream>>>(PART, CH);
    kfinal<<<dim3(256), dim3(64), 0, stream>>>(wsf, F, F1, F2, SPm, CH, out);
}